// Round 1
// baseline (545.214 us; speedup 1.0000x reference)
//
#include <hip/hip_runtime.h>
#include <hip/hip_bf16.h>
#include <math.h>

#define B_SZ   8192
#define S_SZ   16
#define D_SZ   128
#define HID_SZ 1024
#define NUMF_SZ 103
#define GCN_SZ 40
#define G_B    2                 // batch elements per block (32 rows)
#define NBLK   (B_SZ / G_B)      // 4096 blocks
#define R_SZ   (16 * G_B)        // 32 rows
#define STRD   136               // LDS row stride (shorts), pad 8

typedef short bh8 __attribute__((ext_vector_type(8)));   // 8 bf16 (4 VGPRs)
typedef float fx4 __attribute__((ext_vector_type(4)));   // MFMA accumulator

__device__ __forceinline__ fx4 mfma16(bh8 a, bh8 b, fx4 c) {
    return __builtin_amdgcn_mfma_f32_16x16x32_bf16(a, b, c, 0, 0, 0);
}

// fp32 -> bf16 bits via native conversion (RNE on gfx950, 1 VALU op)
__device__ __forceinline__ unsigned short f2b(float f) {
    union { __hip_bfloat16 b; unsigned short u; } cv;
    cv.b = __float2bfloat16(f);
    return cv.u;
}
__device__ __forceinline__ float bu2f(unsigned short u) {
    return __uint_as_float(((unsigned)u) << 16);
}

// Swizzle all weights into B-fragment-linear bf16 order:
//   QKVO : [l][nt(8)][ks(4)][lane(64)][e(8)]   (nt = n/16, k = ks*32 + q*8 + e)
//   W1   : [l][nt(64)][ks(4)][lane][e]
//   W2   : [l][nt(8)][kt(32)][lane][e]
// so a wave's fragment load is one contiguous 1KB block (lane*16B).
__global__ __launch_bounds__(256) void prep_weights(
    const float* __restrict__ Wq, const float* __restrict__ Wk,
    const float* __restrict__ Wv, const float* __restrict__ Wo,
    const float* __restrict__ W1, const float* __restrict__ W2,
    unsigned short* __restrict__ WswQ, unsigned short* __restrict__ WswK,
    unsigned short* __restrict__ WswV, unsigned short* __restrict__ WswO,
    unsigned short* __restrict__ Wsw1, unsigned short* __restrict__ Wsw2,
    float* __restrict__ PEt)
{
    int i = blockIdx.x * 256 + threadIdx.x;
    if (i < 2048) {  // PE table [16][128]
        int s = i >> 7, c = i & 127;
        float expo = (float)((c >> 1) * 2) * (1.0f / 128.0f);
        float denom = powf(10000.0f, expo);
        float ang = (float)s / denom;
        PEt[i] = (c & 1) ? cosf(ang) : sinf(ang);
    }
    if (i < 2 * 16384) {   // QKVO, dst-driven
        int l = i >> 14, r = i & 16383;
        int nt = r >> 11, ks = (r >> 9) & 3, lane = (r >> 3) & 63, e = r & 7;
        int k = ks * 32 + (lane >> 4) * 8 + e;
        int n = nt * 16 + (lane & 15);
        int s = l * 16384 + k * 128 + n;
        WswQ[i] = f2b(Wq[s]); WswK[i] = f2b(Wk[s]);
        WswV[i] = f2b(Wv[s]); WswO[i] = f2b(Wo[s]);
    }
    {   // W1: src [l][k=128][n=1024]
        int l = i >> 17, r = i & 131071;
        int nt = r >> 11, ks = (r >> 9) & 3, lane = (r >> 3) & 63, e = r & 7;
        int k = ks * 32 + (lane >> 4) * 8 + e;
        int n = nt * 16 + (lane & 15);
        Wsw1[i] = f2b(W1[l * 131072 + k * 1024 + n]);
    }
    {   // W2: src [l][k=1024][n=128]
        int l = i >> 17, r = i & 131071;
        int nt = r >> 14, kt = (r >> 9) & 31, lane = (r >> 3) & 63, e = r & 7;
        int k = kt * 32 + (lane >> 4) * 8 + e;
        int n = nt * 16 + (lane & 15);
        Wsw2[i] = f2b(W2[l * 131072 + k * 128 + n]);
    }
}

// Block = 4 waves, 2 batch elements (32 rows). Waves split N (2 n-tiles each).
// LDS ~36 KB -> 4 blocks/CU (16 waves/CU) for latency hiding.
__global__ __launch_bounds__(256, 4) void encoder_fused(
    const float* __restrict__ x, const float* __restrict__ gcn,
    const float* __restrict__ bq, const float* __restrict__ bk,
    const float* __restrict__ bv, const float* __restrict__ bo,
    const float* __restrict__ ln1g, const float* __restrict__ ln1b,
    const float* __restrict__ b1, const float* __restrict__ b2p,
    const float* __restrict__ ln2g, const float* __restrict__ ln2b,
    const float* __restrict__ Wf,
    const unsigned short* __restrict__ WswQ, const unsigned short* __restrict__ WswK,
    const unsigned short* __restrict__ WswV, const unsigned short* __restrict__ WswO,
    const unsigned short* __restrict__ Wsw1, const unsigned short* __restrict__ Wsw2,
    const float* __restrict__ PEt,
    float* __restrict__ acc1)
{
    __shared__ unsigned short ACT[R_SZ][STRD];  // activations / LN2 output
    __shared__ unsigned short Qb[R_SZ][STRD];   // Q -> ctx -> FF1 chunk (even)
    __shared__ unsigned short Kb[R_SZ][STRD];   // K -> H (post-LN1)
    __shared__ unsigned short Vb[R_SZ][STRD];   // V -> FF1 chunk (odd)
    __shared__ float LNp[R_SZ][4][2];           // per-row per-wave (sum, sumsq)
    __shared__ float LNs[R_SZ][2];              // per-row (mean, inv)

    const int t = threadIdx.x;
    const int w = t >> 6, lane = t & 63;
    const int q = lane >> 4, ln = lane & 15;
    const int bbase = blockIdx.x * G_B;

    // ---- load x + PE -> ACT (bf16) ----
    {
        const float4* xb = (const float4*)(x + (size_t)bbase * 2048);
        const float4* pe4 = (const float4*)PEt;
#pragma unroll
        for (int i = 0; i < 4; ++i) {
            int f4 = i * 256 + t;                  // 0..1023
            float4 xv = xb[f4];
            float4 pv = pe4[f4 & 511];
            int flat = f4 * 4;
            int row = flat >> 7, col = flat & 127;
            ushort4 pk = {f2b(xv.x + pv.x), f2b(xv.y + pv.y),
                          f2b(xv.z + pv.z), f2b(xv.w + pv.w)};
            *(ushort4*)&ACT[row][col] = pk;
        }
    }
    __syncthreads();

    for (int l = 0; l < 2; ++l) {
        // ================= QKV =================
        {
            bh8 afr[2][4];
#pragma unroll
            for (int mt = 0; mt < 2; ++mt)
#pragma unroll
                for (int ks = 0; ks < 4; ++ks)
                    afr[mt][ks] = *(const bh8*)&ACT[mt * 16 + ln][ks * 32 + q * 8];
            const unsigned short* Wm[3] = {WswQ + l * 16384, WswK + l * 16384, WswV + l * 16384};
            const float* bias3[3] = {bq + l * 128, bk + l * 128, bv + l * 128};
#pragma unroll
            for (int mtx = 0; mtx < 3; ++mtx) {
                unsigned short (*dst)[STRD] = (mtx == 0) ? Qb : (mtx == 1) ? Kb : Vb;
#pragma unroll
                for (int i2 = 0; i2 < 2; ++i2) {
                    int nt = w * 2 + i2;
                    bh8 wfr[4];
#pragma unroll
                    for (int ks = 0; ks < 4; ++ks)
                        wfr[ks] = *(const bh8*)(Wm[mtx] + ((nt * 4 + ks) * 64 + lane) * 8);
                    int n = nt * 16 + ln;
                    float bb = bias3[mtx][n];
#pragma unroll
                    for (int mt = 0; mt < 2; ++mt) {
                        fx4 acc = {0.f, 0.f, 0.f, 0.f};
#pragma unroll
                        for (int ks = 0; ks < 4; ++ks) acc = mfma16(afr[mt][ks], wfr[ks], acc);
#pragma unroll
                        for (int r2 = 0; r2 < 4; ++r2)
                            dst[mt * 16 + q * 4 + r2][n] = f2b(acc[r2] + bb);
                    }
                }
            }
        }
        __syncthreads();

        // ===== attention (verified raw-reshape): 2 waves per batch element,
        // 1 (head g, seq u) pair per lane.
        {
            const int e = w >> 1;
            const int base = e * 16;
            const int pid = ((w & 1) << 6) | lane;   // 0..127 within batch e
            const int g = pid >> 4, u = pid & 15;
            const int qsr = base + 2 * g + (u >> 3), qc = (u & 7) * 16;
            float qr[16];
            {
                bh8 a0 = *(const bh8*)&Qb[qsr][qc];
                bh8 a1 = *(const bh8*)&Qb[qsr][qc + 8];
#pragma unroll
                for (int e8 = 0; e8 < 8; ++e8) {
                    qr[e8] = bu2f((unsigned short)a0[e8]);
                    qr[8 + e8] = bu2f((unsigned short)a1[e8]);
                }
            }
            float p[16];
#pragma unroll
            for (int tp = 0; tp < 16; ++tp) {
                int ksr = base + 2 * g + (tp >> 3), kc = (tp & 7) * 16;
                bh8 k0 = *(const bh8*)&Kb[ksr][kc];
                bh8 k1 = *(const bh8*)&Kb[ksr][kc + 8];
                float d = 0.f;
#pragma unroll
                for (int e8 = 0; e8 < 8; ++e8)
                    d = fmaf(qr[e8], bu2f((unsigned short)k0[e8]), d);
#pragma unroll
                for (int e8 = 0; e8 < 8; ++e8)
                    d = fmaf(qr[8 + e8], bu2f((unsigned short)k1[e8]), d);
                p[tp] = d * 0.25f;
            }
            float mx = -1e30f;
#pragma unroll
            for (int tp = 0; tp < 16; ++tp) mx = fmaxf(mx, p[tp]);
            float sum = 0.f;
#pragma unroll
            for (int tp = 0; tp < 16; ++tp) { p[tp] = __expf(p[tp] - mx); sum += p[tp]; }
            float is = 1.0f / sum;
            float ctx[16];
#pragma unroll
            for (int e8 = 0; e8 < 16; ++e8) ctx[e8] = 0.f;
#pragma unroll
            for (int tp = 0; tp < 16; ++tp) {
                int vsr = base + 2 * g + (tp >> 3), vc = (tp & 7) * 16;
                bh8 v0 = *(const bh8*)&Vb[vsr][vc];
                bh8 v1 = *(const bh8*)&Vb[vsr][vc + 8];
                float pw = p[tp] * is;
#pragma unroll
                for (int e8 = 0; e8 < 8; ++e8) {
                    ctx[e8]     = fmaf(pw, bu2f((unsigned short)v0[e8]), ctx[e8]);
                    ctx[8 + e8] = fmaf(pw, bu2f((unsigned short)v1[e8]), ctx[8 + e8]);
                }
            }
            bh8 c0, c1;
#pragma unroll
            for (int e8 = 0; e8 < 8; ++e8) {
                c0[e8] = (short)f2b(ctx[e8]);
                c1[e8] = (short)f2b(ctx[8 + e8]);
            }
            *(bh8*)&Qb[qsr][qc] = c0;
            *(bh8*)&Qb[qsr][qc + 8] = c1;
        }
        __syncthreads();

        // ================= O-proj + residual + LN1 -> Kb (H) ================
        fx4 Cv[2][2];
        {
            bh8 cfr[2][4];
#pragma unroll
            for (int mt = 0; mt < 2; ++mt)
#pragma unroll
                for (int ks = 0; ks < 4; ++ks)
                    cfr[mt][ks] = *(const bh8*)&Qb[mt * 16 + ln][ks * 32 + q * 8];
#pragma unroll
            for (int i2 = 0; i2 < 2; ++i2) {
                int nt = w * 2 + i2, n = nt * 16 + ln;
                bh8 wfr[4];
#pragma unroll
                for (int ks = 0; ks < 4; ++ks)
                    wfr[ks] = *(const bh8*)(WswO + l * 16384 + ((nt * 4 + ks) * 64 + lane) * 8);
                float bb = bo[l * 128 + n];
#pragma unroll
                for (int mt = 0; mt < 2; ++mt) {
                    fx4 acc = {0.f, 0.f, 0.f, 0.f};
#pragma unroll
                    for (int ks = 0; ks < 4; ++ks) acc = mfma16(cfr[mt][ks], wfr[ks], acc);
#pragma unroll
                    for (int r2 = 0; r2 < 4; ++r2)
                        Cv[i2][mt][r2] = acc[r2] + bb +
                            bu2f(ACT[mt * 16 + q * 4 + r2][n]);
                }
            }
        }
        // LN1 partials
#pragma unroll
        for (int mt = 0; mt < 2; ++mt) {
            float s4[4], v4[4];
#pragma unroll
            for (int r2 = 0; r2 < 4; ++r2) {
                float a0 = Cv[0][mt][r2], a1 = Cv[1][mt][r2];
                float s = a0 + a1, v = a0 * a0 + a1 * a1;
#pragma unroll
                for (int m = 1; m < 16; m <<= 1) { s += __shfl_xor(s, m); v += __shfl_xor(v, m); }
                s4[r2] = s; v4[r2] = v;
            }
            if (ln < 8)
                LNp[mt * 16 + q * 4 + (ln >> 1)][w][ln & 1] = (ln & 1) ? v4[ln >> 1] : s4[ln >> 1];
        }
        __syncthreads();
        if (t < R_SZ) {
            float s = LNp[t][0][0] + LNp[t][1][0] + LNp[t][2][0] + LNp[t][3][0];
            float v = LNp[t][0][1] + LNp[t][1][1] + LNp[t][2][1] + LNp[t][3][1];
            float mean = s * (1.0f / 128.0f);
            LNs[t][0] = mean;
            LNs[t][1] = rsqrtf(v * (1.0f / 128.0f) - mean * mean + 1e-5f);
        }
        __syncthreads();
#pragma unroll
        for (int i2 = 0; i2 < 2; ++i2) {
            int n = (w * 2 + i2) * 16 + ln;
            float gg = ln1g[l * 128 + n], be = ln1b[l * 128 + n];
#pragma unroll
            for (int mt = 0; mt < 2; ++mt)
#pragma unroll
                for (int r2 = 0; r2 < 4; ++r2) {
                    int row = mt * 16 + q * 4 + r2;
                    Kb[row][n] = f2b((Cv[i2][mt][r2] - LNs[row][0]) * LNs[row][1] * gg + be);
                }
        }
        __syncthreads();

        // ================= FF (8 chunks of 128 hidden) ======================
        // H fragments loop-invariant: hoist. FF1 chunks double-buffer Qb/Vb
        // (Vb dead after attention) -> only ONE barrier per chunk: the
        // write->read hazard; re-write of the same buffer at ch+2 is ordered
        // by the ch+1 barrier (waitcnts drain before s_barrier).
        bh8 hfr[2][4];
#pragma unroll
        for (int mt = 0; mt < 2; ++mt)
#pragma unroll
            for (int ks = 0; ks < 4; ++ks)
                hfr[mt][ks] = *(const bh8*)&Kb[mt * 16 + ln][ks * 32 + q * 8];
        fx4 f2a[2][2];
#pragma unroll
        for (int i2 = 0; i2 < 2; ++i2)
#pragma unroll
            for (int mt = 0; mt < 2; ++mt) f2a[i2][mt] = fx4{0.f, 0.f, 0.f, 0.f};
        for (int ch = 0; ch < 8; ++ch) {
            unsigned short (*dst)[STRD] = (ch & 1) ? Vb : Qb;
            bh8 w1fr[2][4];
#pragma unroll
            for (int i2 = 0; i2 < 2; ++i2) {
                int ntg = ch * 8 + w * 2 + i2;
#pragma unroll
                for (int ks = 0; ks < 4; ++ks)
                    w1fr[i2][ks] = *(const bh8*)(Wsw1 + l * 131072 + ((ntg * 4 + ks) * 64 + lane) * 8);
            }
#pragma unroll
            for (int mt = 0; mt < 2; ++mt) {
#pragma unroll
                for (int i2 = 0; i2 < 2; ++i2) {
                    fx4 acc = {0.f, 0.f, 0.f, 0.f};
#pragma unroll
                    for (int ks = 0; ks < 4; ++ks) acc = mfma16(hfr[mt][ks], w1fr[i2][ks], acc);
                    int nl = (w * 2 + i2) * 16 + ln;
                    float bb = b1[l * HID_SZ + ch * 128 + nl];
#pragma unroll
                    for (int r2 = 0; r2 < 4; ++r2) {
                        float vv = acc[r2] + bb;
                        dst[mt * 16 + q * 4 + r2][nl] = f2b(vv > 0.f ? vv : 0.f);
                    }
                }
            }
            __syncthreads();
            bh8 w2fr[2][4];
#pragma unroll
            for (int i2 = 0; i2 < 2; ++i2)
#pragma unroll
                for (int ks = 0; ks < 4; ++ks)
                    w2fr[i2][ks] = *(const bh8*)(Wsw2 + l * 131072 +
                        (((w * 2 + i2) * 32 + ch * 4 + ks) * 64 + lane) * 8);
#pragma unroll
            for (int mt = 0; mt < 2; ++mt) {
                bh8 ffr[4];
#pragma unroll
                for (int ks = 0; ks < 4; ++ks)
                    ffr[ks] = *(const bh8*)&dst[mt * 16 + ln][ks * 32 + q * 8];
#pragma unroll
                for (int i2 = 0; i2 < 2; ++i2)
#pragma unroll
                    for (int ks = 0; ks < 4; ++ks)
                        f2a[i2][mt] = mfma16(ffr[ks], w2fr[i2][ks], f2a[i2][mt]);
            }
            // no trailing barrier: double-buffered
        }
        // epilogue: + b2 + H residual, LN2 -> ACT
        fx4 Cv2[2][2];
#pragma unroll
        for (int i2 = 0; i2 < 2; ++i2) {
            int n = (w * 2 + i2) * 16 + ln;
            float bb = b2p[l * 128 + n];
#pragma unroll
            for (int mt = 0; mt < 2; ++mt)
#pragma unroll
                for (int r2 = 0; r2 < 4; ++r2)
                    Cv2[i2][mt][r2] = f2a[i2][mt][r2] + bb +
                        bu2f(Kb[mt * 16 + q * 4 + r2][n]);
        }
#pragma unroll
        for (int mt = 0; mt < 2; ++mt) {
            float s4[4], v4[4];
#pragma unroll
            for (int r2 = 0; r2 < 4; ++r2) {
                float a0 = Cv2[0][mt][r2], a1 = Cv2[1][mt][r2];
                float s = a0 + a1, v = a0 * a0 + a1 * a1;
#pragma unroll
                for (int m = 1; m < 16; m <<= 1) { s += __shfl_xor(s, m); v += __shfl_xor(v, m); }
                s4[r2] = s; v4[r2] = v;
            }
            if (ln < 8)
                LNp[mt * 16 + q * 4 + (ln >> 1)][w][ln & 1] = (ln & 1) ? v4[ln >> 1] : s4[ln >> 1];
        }
        __syncthreads();
        if (t < R_SZ) {
            float s = LNp[t][0][0] + LNp[t][1][0] + LNp[t][2][0] + LNp[t][3][0];
            float v = LNp[t][0][1] + LNp[t][1][1] + LNp[t][2][1] + LNp[t][3][1];
            float mean = s * (1.0f / 128.0f);
            LNs[t][0] = mean;
            LNs[t][1] = rsqrtf(v * (1.0f / 128.0f) - mean * mean + 1e-5f);
        }
        __syncthreads();
#pragma unroll
        for (int i2 = 0; i2 < 2; ++i2) {
            int n = (w * 2 + i2) * 16 + ln;
            float gg = ln2g[l * 128 + n], be = ln2b[l * 128 + n];
#pragma unroll
            for (int mt = 0; mt < 2; ++mt)
#pragma unroll
                for (int r2 = 0; r2 < 4; ++r2) {
                    int row = mt * 16 + q * 4 + r2;
                    ACT[row][n] = f2b((Cv2[i2][mt][r2] - LNs[row][0]) * LNs[row][1] * gg + be);
                }
        }
        __syncthreads();
    }

    // ============ head partial dot: 2 waves per batch element ==============
    {
        const int e = w >> 1, h2 = w & 1;
        int bg = bbase + e;
        float part = 0.f;
        int r = h2 * 8 + (lane >> 3), c0 = (lane & 7) * 16;
#pragma unroll
        for (int i = 0; i < 2; ++i) {
            bh8 av = *(const bh8*)&ACT[e * 16 + r][c0 + i * 8];
            int fl = r * 128 + c0 + i * 8;
#pragma unroll
            for (int e8 = 0; e8 < 8; ++e8)
                part = fmaf(bu2f((unsigned short)av[e8]), Wf[fl + e8], part);
        }
        if (lane < 20) {
            int gi = h2 * 20 + lane;
            part = fmaf(gcn[(size_t)bg * GCN_SZ + gi], Wf[2048 + gi], part);
        }
#pragma unroll
        for (int off = 32; off; off >>= 1) part += __shfl_xor(part, off);
        if (lane == 0) LNs[w][0] = part;
    }
    __syncthreads();
    if (t < G_B)
        acc1[bbase + t] = LNs[2 * t][0] + LNs[2 * t + 1][0];
}

// BN batch statistics: per-column sum / sumsq of n = num @ Wn + bnum.
// Also stores n to workspace (if it fits) so final_kernel needn't recompute.
__global__ __launch_bounds__(256) void num_stats_kernel(
    const float* __restrict__ num, const float* __restrict__ Wn,
    const float* __restrict__ bnum,
    float* __restrict__ ssum, float* __restrict__ ssq,
    float* __restrict__ nws, int have_nws)
{
    __shared__ float NUM[16][NUMF_SZ + 1];
    __shared__ float cred[4][128];
    const int t = threadIdx.x;
    const int b0 = blockIdx.x * 16;
    const int j = t & 127, sg = t >> 7, s0 = sg * 8;

    for (int idx = t; idx < 16 * NUMF_SZ; idx += 256) {
        int r = idx / NUMF_SZ, f = idx - r * NUMF_SZ;
        NUM[r][f] = num[(size_t)(b0 + r) * NUMF_SZ + f];
    }
    __syncthreads();

    float acc[8];
    float bnv = bnum[j];
#pragma unroll
    for (int r = 0; r < 8; ++r) acc[r] = bnv;
    for (int f = 0; f < NUMF_SZ; ++f) {
        float w = Wn[f * 128 + j];
#pragma unroll
        for (int r = 0; r < 8; ++r) acc[r] = fmaf(NUM[s0 + r][f], w, acc[r]);
    }
    if (have_nws) {
#pragma unroll
        for (int r = 0; r < 8; ++r)
            nws[(size_t)(b0 + s0 + r) * 128 + j] = acc[r];
    }
    float lsum = 0.f, lsq = 0.f;
#pragma unroll
    for (int r = 0; r < 8; ++r) {
        lsum += acc[r];
        lsq = fmaf(acc[r], acc[r], lsq);
    }
    cred[sg][j] = lsum;
    cred[2 + sg][j] = lsq;
    __syncthreads();
    if (sg == 0) atomicAdd(&ssum[j], cred[0][j] + cred[1][j]);
    else         atomicAdd(&ssq[j],  cred[2][j] + cred[3][j]);
}

// BN(train-mode, biased var) on precomputed n, final dot + sigmoid.
__global__ __launch_bounds__(128) void final_kernel(
    const float* __restrict__ num, const float* __restrict__ Wn,
    const float* __restrict__ bnum,
    const float* __restrict__ ssum, const float* __restrict__ ssq,
    const float* __restrict__ gamma, const float* __restrict__ beta,
    const float* __restrict__ Wf, const float* __restrict__ bfin,
    const float* __restrict__ acc1, float* __restrict__ out,
    const float* __restrict__ nws, int have_nws)
{
    const int b = blockIdx.x, jj = threadIdx.x;
    __shared__ float red2[2];
    __shared__ float NUMr[NUMF_SZ];

    float nv;
    if (have_nws) {
        nv = nws[(size_t)b * 128 + jj];
    } else {
        if (jj < NUMF_SZ) NUMr[jj] = num[(size_t)b * NUMF_SZ + jj];
        __syncthreads();
        nv = bnum[jj];
        for (int f = 0; f < NUMF_SZ; ++f)
            nv = fmaf(NUMr[f], Wn[f * 128 + jj], nv);
    }

    float mean = ssum[jj] * (1.0f / (float)B_SZ);
    float var = ssq[jj] * (1.0f / (float)B_SZ) - mean * mean;
    float bnv = (nv - mean) * rsqrtf(var + 1e-5f) * gamma[jj] + beta[jj];
    float v = bnv * Wf[2088 + jj];
#pragma unroll
    for (int o = 32; o; o >>= 1) v += __shfl_down(v, o);
    if ((jj & 63) == 0) red2[jj >> 6] = v;
    __syncthreads();
    if (jj == 0) {
        float z = acc1[b] + red2[0] + red2[1] + bfin[0];
        out[b] = 1.0f / (1.0f + __expf(-z));
    }
}

extern "C" void kernel_launch(void* const* d_in, const int* in_sizes, int n_in,
                              void* d_out, int out_size, void* d_ws, size_t ws_size,
                              hipStream_t stream)
{
    const float* x    = (const float*)d_in[0];
    const float* gcn  = (const float*)d_in[1];
    const float* num  = (const float*)d_in[2];
    const float* Wq   = (const float*)d_in[3];
    const float* bq   = (const float*)d_in[4];
    const float* Wk   = (const float*)d_in[5];
    const float* bk   = (const float*)d_in[6];
    const float* Wv   = (const float*)d_in[7];
    const float* bv   = (const float*)d_in[8];
    const float* Wo   = (const float*)d_in[9];
    const float* bo   = (const float*)d_in[10];
    const float* ln1g = (const float*)d_in[11];
    const float* ln1b = (const float*)d_in[12];
    const float* W1   = (const float*)d_in[13];
    const float* b1   = (const float*)d_in[14];
    const float* W2   = (const float*)d_in[15];
    const float* b2p  = (const float*)d_in[16];
    const float* ln2g = (const float*)d_in[17];
    const float* ln2b = (const float*)d_in[18];
    const float* Wn   = (const float*)d_in[19];
    const float* bnum = (const float*)d_in[20];
    const float* bng  = (const float*)d_in[21];
    const float* bnb  = (const float*)d_in[22];
    const float* Wf   = (const float*)d_in[23];
    const float* bfin = (const float*)d_in[24];

    // ws: acc1 (8192 f32) | ssum | ssq | pad to 40960 | swizzled bf16 weights
    //     | PE (8 KB) | n precompute (4 MB, optional)
    float* acc1 = (float*)d_ws;
    float* ssum = acc1 + B_SZ;
    float* ssq  = ssum + 128;
    unsigned short* wb = (unsigned short*)((char*)d_ws + 40960);
    unsigned short* WswQ = wb;
    unsigned short* WswK = wb + 32768;
    unsigned short* WswV = wb + 65536;
    unsigned short* WswO = wb + 98304;
    unsigned short* Wsw1 = wb + 131072;
    unsigned short* Wsw2 = wb + 393216;
    float* PEt = (float*)((char*)d_ws + 40960 + 1310720);
    const size_t nws_off = 40960 + 1310720 + 8192;
    float* nws = (float*)((char*)d_ws + nws_off);
    const int have_nws = (ws_size >= nws_off + (size_t)B_SZ * 128 * sizeof(float)) ? 1 : 0;

    hipMemsetAsync(ssum, 0, 2 * 128 * sizeof(float), stream);
    prep_weights<<<1024, 256, 0, stream>>>(Wq, Wk, Wv, Wo, W1, W2,
        WswQ, WswK, WswV, WswO, Wsw1, Wsw2, PEt);
    encoder_fused<<<NBLK, 256, 0, stream>>>(x, gcn, bq, bk, bv, bo,
        ln1g, ln1b, b1, b2p, ln2g, ln2b, Wf,
        WswQ, WswK, WswV, WswO, Wsw1, Wsw2, PEt, acc1);
    num_stats_kernel<<<B_SZ / 16, 256, 0, stream>>>(num, Wn, bnum, ssum, ssq,
        nws, have_nws);
    final_kernel<<<B_SZ, 128, 0, stream>>>(num, Wn, bnum, ssum, ssq, bng, bnb,
        Wf, bfin, acc1, (float*)d_out, nws, have_nws);
}

// Round 2
// 481.171 us; speedup vs baseline: 1.1331x; 1.1331x over previous
//
#include <hip/hip_runtime.h>
#include <hip/hip_bf16.h>
#include <math.h>

#define B_SZ   8192
#define S_SZ   16
#define D_SZ   128
#define HID_SZ 1024
#define NUMF_SZ 103
#define GCN_SZ 40
#define G_B    2                 // batch elements per block (32 rows)
#define NBLK   (B_SZ / G_B)      // 4096 blocks
#define R_SZ   (16 * G_B)        // 32 rows
#define STRD   136               // LDS row stride (shorts), pad 8

typedef short bh8 __attribute__((ext_vector_type(8)));   // 8 bf16 (4 VGPRs)
typedef float fx4 __attribute__((ext_vector_type(4)));   // MFMA accumulator

__device__ __forceinline__ fx4 mfma16(bh8 a, bh8 b, fx4 c) {
    return __builtin_amdgcn_mfma_f32_16x16x32_bf16(a, b, c, 0, 0, 0);
}

// fp32 -> bf16 bits via native conversion (RNE on gfx950, 1 VALU op)
__device__ __forceinline__ unsigned short f2b(float f) {
    union { __hip_bfloat16 b; unsigned short u; } cv;
    cv.b = __float2bfloat16(f);
    return cv.u;
}
__device__ __forceinline__ float bu2f(unsigned short u) {
    return __uint_as_float(((unsigned)u) << 16);
}

// Swizzle all weights into B-fragment-linear bf16 order:
//   QKVO : [l][nt(8)][ks(4)][lane(64)][e(8)]   (nt = n/16, k = ks*32 + q*8 + e)
//   W1   : [l][nt(64)][ks(4)][lane][e]
//   W2   : [l][nt(8)][kt(32)][lane][e]
// so a wave's fragment load is one contiguous 1KB block (lane*16B).
__global__ __launch_bounds__(256) void prep_weights(
    const float* __restrict__ Wq, const float* __restrict__ Wk,
    const float* __restrict__ Wv, const float* __restrict__ Wo,
    const float* __restrict__ W1, const float* __restrict__ W2,
    unsigned short* __restrict__ WswQ, unsigned short* __restrict__ WswK,
    unsigned short* __restrict__ WswV, unsigned short* __restrict__ WswO,
    unsigned short* __restrict__ Wsw1, unsigned short* __restrict__ Wsw2,
    float* __restrict__ PEt)
{
    int i = blockIdx.x * 256 + threadIdx.x;
    if (i < 2048) {  // PE table [16][128]
        int s = i >> 7, c = i & 127;
        float expo = (float)((c >> 1) * 2) * (1.0f / 128.0f);
        float denom = powf(10000.0f, expo);
        float ang = (float)s / denom;
        PEt[i] = (c & 1) ? cosf(ang) : sinf(ang);
    }
    if (i < 2 * 16384) {   // QKVO, dst-driven
        int l = i >> 14, r = i & 16383;
        int nt = r >> 11, ks = (r >> 9) & 3, lane = (r >> 3) & 63, e = r & 7;
        int k = ks * 32 + (lane >> 4) * 8 + e;
        int n = nt * 16 + (lane & 15);
        int s = l * 16384 + k * 128 + n;
        WswQ[i] = f2b(Wq[s]); WswK[i] = f2b(Wk[s]);
        WswV[i] = f2b(Wv[s]); WswO[i] = f2b(Wo[s]);
    }
    {   // W1: src [l][k=128][n=1024]
        int l = i >> 17, r = i & 131071;
        int nt = r >> 11, ks = (r >> 9) & 3, lane = (r >> 3) & 63, e = r & 7;
        int k = ks * 32 + (lane >> 4) * 8 + e;
        int n = nt * 16 + (lane & 15);
        Wsw1[i] = f2b(W1[l * 131072 + k * 1024 + n]);
    }
    {   // W2: src [l][k=1024][n=128]
        int l = i >> 17, r = i & 131071;
        int nt = r >> 14, kt = (r >> 9) & 31, lane = (r >> 3) & 63, e = r & 7;
        int k = kt * 32 + (lane >> 4) * 8 + e;
        int n = nt * 16 + (lane & 15);
        Wsw2[i] = f2b(W2[l * 131072 + k * 128 + n]);
    }
}

// Block = 4 waves, 2 batch elements (32 rows). Waves split N (2 n-tiles each).
// LDS ~36 KB. launch_bounds(256,3): VGPR cap ~170 -> NO spills (the (256,4)
// cap of 128 spilled the FF loop -> 600MB scratch traffic, the R1 regression).
__global__ __launch_bounds__(256, 3) void encoder_fused(
    const float* __restrict__ x, const float* __restrict__ gcn,
    const float* __restrict__ bq, const float* __restrict__ bk,
    const float* __restrict__ bv, const float* __restrict__ bo,
    const float* __restrict__ ln1g, const float* __restrict__ ln1b,
    const float* __restrict__ b1, const float* __restrict__ b2p,
    const float* __restrict__ ln2g, const float* __restrict__ ln2b,
    const float* __restrict__ Wf,
    const unsigned short* __restrict__ WswQ, const unsigned short* __restrict__ WswK,
    const unsigned short* __restrict__ WswV, const unsigned short* __restrict__ WswO,
    const unsigned short* __restrict__ Wsw1, const unsigned short* __restrict__ Wsw2,
    const float* __restrict__ PEt,
    float* __restrict__ acc1)
{
    __shared__ unsigned short ACT[R_SZ][STRD];  // activations / LN2 output
    __shared__ unsigned short Qb[R_SZ][STRD];   // Q -> ctx -> FF1 chunk (even)
    __shared__ unsigned short Kb[R_SZ][STRD];   // K -> H (post-LN1)
    __shared__ unsigned short Vb[R_SZ][STRD];   // V -> FF1 chunk (odd)
    __shared__ float LNp[R_SZ][4][2];           // per-row per-wave (sum, sumsq)
    __shared__ float LNs[R_SZ][2];              // per-row (mean, inv)

    const int t = threadIdx.x;
    const int w = t >> 6, lane = t & 63;
    const int q = lane >> 4, ln = lane & 15;
    const int bbase = blockIdx.x * G_B;

    // ---- load x + PE -> ACT (bf16) ----
    {
        const float4* xb = (const float4*)(x + (size_t)bbase * 2048);
        const float4* pe4 = (const float4*)PEt;
#pragma unroll
        for (int i = 0; i < 4; ++i) {
            int f4 = i * 256 + t;                  // 0..1023
            float4 xv = xb[f4];
            float4 pv = pe4[f4 & 511];
            int flat = f4 * 4;
            int row = flat >> 7, col = flat & 127;
            ushort4 pk = {f2b(xv.x + pv.x), f2b(xv.y + pv.y),
                          f2b(xv.z + pv.z), f2b(xv.w + pv.w)};
            *(ushort4*)&ACT[row][col] = pk;
        }
    }
    __syncthreads();

    for (int l = 0; l < 2; ++l) {
        // ================= QKV =================
        {
            bh8 afr[2][4];
#pragma unroll
            for (int mt = 0; mt < 2; ++mt)
#pragma unroll
                for (int ks = 0; ks < 4; ++ks)
                    afr[mt][ks] = *(const bh8*)&ACT[mt * 16 + ln][ks * 32 + q * 8];
            const unsigned short* Wm[3] = {WswQ + l * 16384, WswK + l * 16384, WswV + l * 16384};
            const float* bias3[3] = {bq + l * 128, bk + l * 128, bv + l * 128};
#pragma unroll
            for (int mtx = 0; mtx < 3; ++mtx) {
                unsigned short (*dst)[STRD] = (mtx == 0) ? Qb : (mtx == 1) ? Kb : Vb;
#pragma unroll
                for (int i2 = 0; i2 < 2; ++i2) {
                    int nt = w * 2 + i2;
                    bh8 wfr[4];
#pragma unroll
                    for (int ks = 0; ks < 4; ++ks)
                        wfr[ks] = *(const bh8*)(Wm[mtx] + ((nt * 4 + ks) * 64 + lane) * 8);
                    int n = nt * 16 + ln;
                    float bb = bias3[mtx][n];
#pragma unroll
                    for (int mt = 0; mt < 2; ++mt) {
                        fx4 acc = {0.f, 0.f, 0.f, 0.f};
#pragma unroll
                        for (int ks = 0; ks < 4; ++ks) acc = mfma16(afr[mt][ks], wfr[ks], acc);
#pragma unroll
                        for (int r2 = 0; r2 < 4; ++r2)
                            dst[mt * 16 + q * 4 + r2][n] = f2b(acc[r2] + bb);
                    }
                }
            }
        }
        __syncthreads();

        // ===== attention (verified raw-reshape): 2 waves per batch element,
        // 1 (head g, seq u) pair per lane.
        {
            const int e = w >> 1;
            const int base = e * 16;
            const int pid = ((w & 1) << 6) | lane;   // 0..127 within batch e
            const int g = pid >> 4, u = pid & 15;
            const int qsr = base + 2 * g + (u >> 3), qc = (u & 7) * 16;
            float qr[16];
            {
                bh8 a0 = *(const bh8*)&Qb[qsr][qc];
                bh8 a1 = *(const bh8*)&Qb[qsr][qc + 8];
#pragma unroll
                for (int e8 = 0; e8 < 8; ++e8) {
                    qr[e8] = bu2f((unsigned short)a0[e8]);
                    qr[8 + e8] = bu2f((unsigned short)a1[e8]);
                }
            }
            float p[16];
#pragma unroll
            for (int tp = 0; tp < 16; ++tp) {
                int ksr = base + 2 * g + (tp >> 3), kc = (tp & 7) * 16;
                bh8 k0 = *(const bh8*)&Kb[ksr][kc];
                bh8 k1 = *(const bh8*)&Kb[ksr][kc + 8];
                float d = 0.f;
#pragma unroll
                for (int e8 = 0; e8 < 8; ++e8)
                    d = fmaf(qr[e8], bu2f((unsigned short)k0[e8]), d);
#pragma unroll
                for (int e8 = 0; e8 < 8; ++e8)
                    d = fmaf(qr[8 + e8], bu2f((unsigned short)k1[e8]), d);
                p[tp] = d * 0.25f;
            }
            float mx = -1e30f;
#pragma unroll
            for (int tp = 0; tp < 16; ++tp) mx = fmaxf(mx, p[tp]);
            float sum = 0.f;
#pragma unroll
            for (int tp = 0; tp < 16; ++tp) { p[tp] = __expf(p[tp] - mx); sum += p[tp]; }
            float is = 1.0f / sum;
            float ctx[16];
#pragma unroll
            for (int e8 = 0; e8 < 16; ++e8) ctx[e8] = 0.f;
#pragma unroll
            for (int tp = 0; tp < 16; ++tp) {
                int vsr = base + 2 * g + (tp >> 3), vc = (tp & 7) * 16;
                bh8 v0 = *(const bh8*)&Vb[vsr][vc];
                bh8 v1 = *(const bh8*)&Vb[vsr][vc + 8];
                float pw = p[tp] * is;
#pragma unroll
                for (int e8 = 0; e8 < 8; ++e8) {
                    ctx[e8]     = fmaf(pw, bu2f((unsigned short)v0[e8]), ctx[e8]);
                    ctx[8 + e8] = fmaf(pw, bu2f((unsigned short)v1[e8]), ctx[8 + e8]);
                }
            }
            bh8 c0, c1;
#pragma unroll
            for (int e8 = 0; e8 < 8; ++e8) {
                c0[e8] = (short)f2b(ctx[e8]);
                c1[e8] = (short)f2b(ctx[8 + e8]);
            }
            *(bh8*)&Qb[qsr][qc] = c0;
            *(bh8*)&Qb[qsr][qc + 8] = c1;
        }
        __syncthreads();

        // ================= O-proj + residual + LN1 -> Kb (H) ================
        fx4 Cv[2][2];
        {
            bh8 cfr[2][4];
#pragma unroll
            for (int mt = 0; mt < 2; ++mt)
#pragma unroll
                for (int ks = 0; ks < 4; ++ks)
                    cfr[mt][ks] = *(const bh8*)&Qb[mt * 16 + ln][ks * 32 + q * 8];
#pragma unroll
            for (int i2 = 0; i2 < 2; ++i2) {
                int nt = w * 2 + i2, n = nt * 16 + ln;
                bh8 wfr[4];
#pragma unroll
                for (int ks = 0; ks < 4; ++ks)
                    wfr[ks] = *(const bh8*)(WswO + l * 16384 + ((nt * 4 + ks) * 64 + lane) * 8);
                float bb = bo[l * 128 + n];
#pragma unroll
                for (int mt = 0; mt < 2; ++mt) {
                    fx4 acc = {0.f, 0.f, 0.f, 0.f};
#pragma unroll
                    for (int ks = 0; ks < 4; ++ks) acc = mfma16(cfr[mt][ks], wfr[ks], acc);
#pragma unroll
                    for (int r2 = 0; r2 < 4; ++r2)
                        Cv[i2][mt][r2] = acc[r2] + bb +
                            bu2f(ACT[mt * 16 + q * 4 + r2][n]);
                }
            }
        }
        // LN1 partials
#pragma unroll
        for (int mt = 0; mt < 2; ++mt) {
            float s4[4], v4[4];
#pragma unroll
            for (int r2 = 0; r2 < 4; ++r2) {
                float a0 = Cv[0][mt][r2], a1 = Cv[1][mt][r2];
                float s = a0 + a1, v = a0 * a0 + a1 * a1;
#pragma unroll
                for (int m = 1; m < 16; m <<= 1) { s += __shfl_xor(s, m); v += __shfl_xor(v, m); }
                s4[r2] = s; v4[r2] = v;
            }
            if (ln < 8)
                LNp[mt * 16 + q * 4 + (ln >> 1)][w][ln & 1] = (ln & 1) ? v4[ln >> 1] : s4[ln >> 1];
        }
        __syncthreads();
        if (t < R_SZ) {
            float s = LNp[t][0][0] + LNp[t][1][0] + LNp[t][2][0] + LNp[t][3][0];
            float v = LNp[t][0][1] + LNp[t][1][1] + LNp[t][2][1] + LNp[t][3][1];
            float mean = s * (1.0f / 128.0f);
            LNs[t][0] = mean;
            LNs[t][1] = rsqrtf(v * (1.0f / 128.0f) - mean * mean + 1e-5f);
        }
        __syncthreads();
#pragma unroll
        for (int i2 = 0; i2 < 2; ++i2) {
            int n = (w * 2 + i2) * 16 + ln;
            float gg = ln1g[l * 128 + n], be = ln1b[l * 128 + n];
#pragma unroll
            for (int mt = 0; mt < 2; ++mt)
#pragma unroll
                for (int r2 = 0; r2 < 4; ++r2) {
                    int row = mt * 16 + q * 4 + r2;
                    Kb[row][n] = f2b((Cv[i2][mt][r2] - LNs[row][0]) * LNs[row][1] * gg + be);
                }
        }
        __syncthreads();

        // ================= FF (8 chunks of 128 hidden) ======================
        // H fragments loop-invariant: hoist. FF1 chunks double-buffer Qb/Vb
        // (Vb dead after attention) -> only ONE barrier per chunk: the
        // write->read hazard; re-write of the same buffer at ch+2 is ordered
        // by the ch+1 barrier (waitcnts drain before s_barrier).
        bh8 hfr[2][4];
#pragma unroll
        for (int mt = 0; mt < 2; ++mt)
#pragma unroll
            for (int ks = 0; ks < 4; ++ks)
                hfr[mt][ks] = *(const bh8*)&Kb[mt * 16 + ln][ks * 32 + q * 8];
        fx4 f2a[2][2];
#pragma unroll
        for (int i2 = 0; i2 < 2; ++i2)
#pragma unroll
            for (int mt = 0; mt < 2; ++mt) f2a[i2][mt] = fx4{0.f, 0.f, 0.f, 0.f};
        for (int ch = 0; ch < 8; ++ch) {
            unsigned short (*dst)[STRD] = (ch & 1) ? Vb : Qb;
            bh8 w1fr[2][4];
#pragma unroll
            for (int i2 = 0; i2 < 2; ++i2) {
                int ntg = ch * 8 + w * 2 + i2;
#pragma unroll
                for (int ks = 0; ks < 4; ++ks)
                    w1fr[i2][ks] = *(const bh8*)(Wsw1 + l * 131072 + ((ntg * 4 + ks) * 64 + lane) * 8);
            }
#pragma unroll
            for (int mt = 0; mt < 2; ++mt) {
#pragma unroll
                for (int i2 = 0; i2 < 2; ++i2) {
                    fx4 acc = {0.f, 0.f, 0.f, 0.f};
#pragma unroll
                    for (int ks = 0; ks < 4; ++ks) acc = mfma16(hfr[mt][ks], w1fr[i2][ks], acc);
                    int nl = (w * 2 + i2) * 16 + ln;
                    float bb = b1[l * HID_SZ + ch * 128 + nl];
#pragma unroll
                    for (int r2 = 0; r2 < 4; ++r2) {
                        float vv = acc[r2] + bb;
                        dst[mt * 16 + q * 4 + r2][nl] = f2b(vv > 0.f ? vv : 0.f);
                    }
                }
            }
            __syncthreads();
            bh8 w2fr[2][4];
#pragma unroll
            for (int i2 = 0; i2 < 2; ++i2)
#pragma unroll
                for (int ks = 0; ks < 4; ++ks)
                    w2fr[i2][ks] = *(const bh8*)(Wsw2 + l * 131072 +
                        (((w * 2 + i2) * 32 + ch * 4 + ks) * 64 + lane) * 8);
#pragma unroll
            for (int mt = 0; mt < 2; ++mt) {
                bh8 ffr[4];
#pragma unroll
                for (int ks = 0; ks < 4; ++ks)
                    ffr[ks] = *(const bh8*)&dst[mt * 16 + ln][ks * 32 + q * 8];
#pragma unroll
                for (int i2 = 0; i2 < 2; ++i2)
#pragma unroll
                    for (int ks = 0; ks < 4; ++ks)
                        f2a[i2][mt] = mfma16(ffr[ks], w2fr[i2][ks], f2a[i2][mt]);
            }
            // no trailing barrier: double-buffered
        }
        // epilogue: + b2 + H residual, LN2 -> ACT
        fx4 Cv2[2][2];
#pragma unroll
        for (int i2 = 0; i2 < 2; ++i2) {
            int n = (w * 2 + i2) * 16 + ln;
            float bb = b2p[l * 128 + n];
#pragma unroll
            for (int mt = 0; mt < 2; ++mt)
#pragma unroll
                for (int r2 = 0; r2 < 4; ++r2)
                    Cv2[i2][mt][r2] = f2a[i2][mt][r2] + bb +
                        bu2f(Kb[mt * 16 + q * 4 + r2][n]);
        }
#pragma unroll
        for (int mt = 0; mt < 2; ++mt) {
            float s4[4], v4[4];
#pragma unroll
            for (int r2 = 0; r2 < 4; ++r2) {
                float a0 = Cv2[0][mt][r2], a1 = Cv2[1][mt][r2];
                float s = a0 + a1, v = a0 * a0 + a1 * a1;
#pragma unroll
                for (int m = 1; m < 16; m <<= 1) { s += __shfl_xor(s, m); v += __shfl_xor(v, m); }
                s4[r2] = s; v4[r2] = v;
            }
            if (ln < 8)
                LNp[mt * 16 + q * 4 + (ln >> 1)][w][ln & 1] = (ln & 1) ? v4[ln >> 1] : s4[ln >> 1];
        }
        __syncthreads();
        if (t < R_SZ) {
            float s = LNp[t][0][0] + LNp[t][1][0] + LNp[t][2][0] + LNp[t][3][0];
            float v = LNp[t][0][1] + LNp[t][1][1] + LNp[t][2][1] + LNp[t][3][1];
            float mean = s * (1.0f / 128.0f);
            LNs[t][0] = mean;
            LNs[t][1] = rsqrtf(v * (1.0f / 128.0f) - mean * mean + 1e-5f);
        }
        __syncthreads();
#pragma unroll
        for (int i2 = 0; i2 < 2; ++i2) {
            int n = (w * 2 + i2) * 16 + ln;
            float gg = ln2g[l * 128 + n], be = ln2b[l * 128 + n];
#pragma unroll
            for (int mt = 0; mt < 2; ++mt)
#pragma unroll
                for (int r2 = 0; r2 < 4; ++r2) {
                    int row = mt * 16 + q * 4 + r2;
                    ACT[row][n] = f2b((Cv2[i2][mt][r2] - LNs[row][0]) * LNs[row][1] * gg + be);
                }
        }
        __syncthreads();
    }

    // ============ head partial dot: 2 waves per batch element ==============
    {
        const int e = w >> 1, h2 = w & 1;
        int bg = bbase + e;
        float part = 0.f;
        int r = h2 * 8 + (lane >> 3), c0 = (lane & 7) * 16;
#pragma unroll
        for (int i = 0; i < 2; ++i) {
            bh8 av = *(const bh8*)&ACT[e * 16 + r][c0 + i * 8];
            int fl = r * 128 + c0 + i * 8;
#pragma unroll
            for (int e8 = 0; e8 < 8; ++e8)
                part = fmaf(bu2f((unsigned short)av[e8]), Wf[fl + e8], part);
        }
        if (lane < 20) {
            int gi = h2 * 20 + lane;
            part = fmaf(gcn[(size_t)bg * GCN_SZ + gi], Wf[2048 + gi], part);
        }
#pragma unroll
        for (int off = 32; off; off >>= 1) part += __shfl_xor(part, off);
        if (lane == 0) LNs[w][0] = part;
    }
    __syncthreads();
    if (t < G_B)
        acc1[bbase + t] = LNs[2 * t][0] + LNs[2 * t + 1][0];
}

// BN batch statistics: per-column sum / sumsq of n = num @ Wn + bnum.
// Also stores n to workspace (if it fits) so the final pass needn't recompute.
__global__ __launch_bounds__(256) void num_stats_kernel(
    const float* __restrict__ num, const float* __restrict__ Wn,
    const float* __restrict__ bnum,
    float* __restrict__ ssum, float* __restrict__ ssq,
    float* __restrict__ nws, int have_nws)
{
    __shared__ float NUM[16][NUMF_SZ + 1];
    __shared__ float cred[4][128];
    const int t = threadIdx.x;
    const int b0 = blockIdx.x * 16;
    const int j = t & 127, sg = t >> 7, s0 = sg * 8;

    for (int idx = t; idx < 16 * NUMF_SZ; idx += 256) {
        int r = idx / NUMF_SZ, f = idx - r * NUMF_SZ;
        NUM[r][f] = num[(size_t)(b0 + r) * NUMF_SZ + f];
    }
    __syncthreads();

    float acc[8];
    float bnv = bnum[j];
#pragma unroll
    for (int r = 0; r < 8; ++r) acc[r] = bnv;
    for (int f = 0; f < NUMF_SZ; ++f) {
        float w = Wn[f * 128 + j];
#pragma unroll
        for (int r = 0; r < 8; ++r) acc[r] = fmaf(NUM[s0 + r][f], w, acc[r]);
    }
    if (have_nws) {
#pragma unroll
        for (int r = 0; r < 8; ++r)
            nws[(size_t)(b0 + s0 + r) * 128 + j] = acc[r];
    }
    float lsum = 0.f, lsq = 0.f;
#pragma unroll
    for (int r = 0; r < 8; ++r) {
        lsum += acc[r];
        lsq = fmaf(acc[r], acc[r], lsq);
    }
    cred[sg][j] = lsum;
    cred[2 + sg][j] = lsq;
    __syncthreads();
    if (sg == 0) atomicAdd(&ssum[j], cred[0][j] + cred[1][j]);
    else         atomicAdd(&ssq[j],  cred[2][j] + cred[3][j]);
}

// Collapse BN into a 128-vector of per-column coefficients + scalar:
//   n_bn . Wf3 = sum_j n_j * c_j + C0,  c_j = inv_j*gamma_j*Wf3_j,
//   C0 = sum_j (beta_j - mean_j*inv_j*gamma_j)*Wf3_j + bf.
__global__ __launch_bounds__(128) void bn_coef_kernel(
    const float* __restrict__ ssum, const float* __restrict__ ssq,
    const float* __restrict__ gamma, const float* __restrict__ beta,
    const float* __restrict__ Wf, const float* __restrict__ bfin,
    float* __restrict__ cvec)
{
    const int j = threadIdx.x;
    __shared__ float red2[2];
    float mean = ssum[j] * (1.0f / (float)B_SZ);
    float var = ssq[j] * (1.0f / (float)B_SZ) - mean * mean;
    float inv = rsqrtf(var + 1e-5f);
    float wj = Wf[2088 + j];
    float gi = gamma[j] * inv;
    cvec[j] = gi * wj;
    float k = (beta[j] - mean * gi) * wj;
#pragma unroll
    for (int o = 32; o; o >>= 1) k += __shfl_down(k, o);
    if ((j & 63) == 0) red2[j >> 6] = k;
    __syncthreads();
    if (j == 0) cvec[128] = red2[0] + red2[1] + bfin[0];
}

// One wave per batch row: dot(nws[b], c) + acc1[b] + C0 -> sigmoid.
__global__ __launch_bounds__(256) void final_fast(
    const float* __restrict__ nws, const float* __restrict__ cvec,
    const float* __restrict__ acc1, float* __restrict__ out)
{
    __shared__ float cs[129];
    const int t = threadIdx.x;
    if (t < 129) cs[t] = cvec[t];
    __syncthreads();
    const int w = t >> 6, lane = t & 63;
    const int b = blockIdx.x * 4 + w;
    const float2* nb = (const float2*)(nws + (size_t)b * 128);
    float2 v = nb[lane];
    float d = v.x * cs[2 * lane] + v.y * cs[2 * lane + 1];
#pragma unroll
    for (int o = 32; o; o >>= 1) d += __shfl_xor(d, o);
    if (lane == 0)
        out[b] = 1.0f / (1.0f + __expf(-(acc1[b] + d + cs[128])));
}

// Fallback (no nws space): recompute n[b], BN, final dot + sigmoid.
__global__ __launch_bounds__(128) void final_kernel(
    const float* __restrict__ num, const float* __restrict__ Wn,
    const float* __restrict__ bnum,
    const float* __restrict__ ssum, const float* __restrict__ ssq,
    const float* __restrict__ gamma, const float* __restrict__ beta,
    const float* __restrict__ Wf, const float* __restrict__ bfin,
    const float* __restrict__ acc1, float* __restrict__ out)
{
    const int b = blockIdx.x, jj = threadIdx.x;
    __shared__ float red2[2];
    __shared__ float NUMr[NUMF_SZ];
    if (jj < NUMF_SZ) NUMr[jj] = num[(size_t)b * NUMF_SZ + jj];
    __syncthreads();
    float nv = bnum[jj];
    for (int f = 0; f < NUMF_SZ; ++f)
        nv = fmaf(NUMr[f], Wn[f * 128 + jj], nv);
    float mean = ssum[jj] * (1.0f / (float)B_SZ);
    float var = ssq[jj] * (1.0f / (float)B_SZ) - mean * mean;
    float bnv = (nv - mean) * rsqrtf(var + 1e-5f) * gamma[jj] + beta[jj];
    float v = bnv * Wf[2088 + jj];
#pragma unroll
    for (int o = 32; o; o >>= 1) v += __shfl_down(v, o);
    if ((jj & 63) == 0) red2[jj >> 6] = v;
    __syncthreads();
    if (jj == 0) {
        float z = acc1[b] + red2[0] + red2[1] + bfin[0];
        out[b] = 1.0f / (1.0f + __expf(-z));
    }
}

extern "C" void kernel_launch(void* const* d_in, const int* in_sizes, int n_in,
                              void* d_out, int out_size, void* d_ws, size_t ws_size,
                              hipStream_t stream)
{
    const float* x    = (const float*)d_in[0];
    const float* gcn  = (const float*)d_in[1];
    const float* num  = (const float*)d_in[2];
    const float* Wq   = (const float*)d_in[3];
    const float* bq   = (const float*)d_in[4];
    const float* Wk   = (const float*)d_in[5];
    const float* bk   = (const float*)d_in[6];
    const float* Wv   = (const float*)d_in[7];
    const float* bv   = (const float*)d_in[8];
    const float* Wo   = (const float*)d_in[9];
    const float* bo   = (const float*)d_in[10];
    const float* ln1g = (const float*)d_in[11];
    const float* ln1b = (const float*)d_in[12];
    const float* W1   = (const float*)d_in[13];
    const float* b1   = (const float*)d_in[14];
    const float* W2   = (const float*)d_in[15];
    const float* b2p  = (const float*)d_in[16];
    const float* ln2g = (const float*)d_in[17];
    const float* ln2b = (const float*)d_in[18];
    const float* Wn   = (const float*)d_in[19];
    const float* bnum = (const float*)d_in[20];
    const float* bng  = (const float*)d_in[21];
    const float* bnb  = (const float*)d_in[22];
    const float* Wf   = (const float*)d_in[23];
    const float* bfin = (const float*)d_in[24];

    // ws: acc1 (8192 f32) | ssum | ssq | pad to 40960 | swizzled bf16 weights
    //     | PE (8 KB) | n precompute (4 MB) | cvec (129 f32)
    float* acc1 = (float*)d_ws;
    float* ssum = acc1 + B_SZ;
    float* ssq  = ssum + 128;
    unsigned short* wb = (unsigned short*)((char*)d_ws + 40960);
    unsigned short* WswQ = wb;
    unsigned short* WswK = wb + 32768;
    unsigned short* WswV = wb + 65536;
    unsigned short* WswO = wb + 98304;
    unsigned short* Wsw1 = wb + 131072;
    unsigned short* Wsw2 = wb + 393216;
    float* PEt = (float*)((char*)d_ws + 40960 + 1310720);
    const size_t nws_off = 40960 + 1310720 + 8192;
    float* nws = (float*)((char*)d_ws + nws_off);
    const size_t cvec_off = nws_off + (size_t)B_SZ * 128 * sizeof(float);
    float* cvec = (float*)((char*)d_ws + cvec_off);
    const int have_nws = (ws_size >= cvec_off + 132 * sizeof(float)) ? 1 : 0;

    hipMemsetAsync(ssum, 0, 2 * 128 * sizeof(float), stream);
    prep_weights<<<1024, 256, 0, stream>>>(Wq, Wk, Wv, Wo, W1, W2,
        WswQ, WswK, WswV, WswO, Wsw1, Wsw2, PEt);
    encoder_fused<<<NBLK, 256, 0, stream>>>(x, gcn, bq, bk, bv, bo,
        ln1g, ln1b, b1, b2p, ln2g, ln2b, Wf,
        WswQ, WswK, WswV, WswO, Wsw1, Wsw2, PEt, acc1);
    num_stats_kernel<<<B_SZ / 16, 256, 0, stream>>>(num, Wn, bnum, ssum, ssq,
        nws, have_nws);
    if (have_nws) {
        bn_coef_kernel<<<1, 128, 0, stream>>>(ssum, ssq, bng, bnb, Wf, bfin, cvec);
        final_fast<<<B_SZ / 4, 256, 0, stream>>>(nws, cvec, acc1, (float*)d_out);
    } else {
        final_kernel<<<B_SZ, 128, 0, stream>>>(num, Wn, bnum, ssum, ssq, bng, bnb,
            Wf, bfin, acc1, (float*)d_out);
    }
}

// Round 3
// 458.925 us; speedup vs baseline: 1.1880x; 1.0485x over previous
//
#include <hip/hip_runtime.h>
#include <hip/hip_bf16.h>
#include <math.h>

#define B_SZ   8192
#define S_SZ   16
#define D_SZ   128
#define HID_SZ 1024
#define NUMF_SZ 103
#define GCN_SZ 40
#define G_B    4                 // batch elements per block (64 rows)
#define NBLK   (B_SZ / G_B)      // 2048 blocks
#define STRD   136               // LDS row stride (shorts), pad 8

typedef short bh8 __attribute__((ext_vector_type(8)));   // 8 bf16 (4 VGPRs)
typedef float fx4 __attribute__((ext_vector_type(4)));   // MFMA accumulator

__device__ __forceinline__ fx4 mfma16(bh8 a, bh8 b, fx4 c) {
    return __builtin_amdgcn_mfma_f32_16x16x32_bf16(a, b, c, 0, 0, 0);
}

// fp32 -> bf16 bits via native conversion (RNE, 1 VALU op)
__device__ __forceinline__ unsigned short f2b(float f) {
    union { __hip_bfloat16 b; unsigned short u; } cv;
    cv.b = __float2bfloat16(f);
    return cv.u;
}
__device__ __forceinline__ float bu2f(unsigned short u) {
    return __uint_as_float(((unsigned)u) << 16);
}

// Swizzle all weights into B-fragment-linear bf16 order:
//   QKVO : [l][nt(8)][ks(4)][lane(64)][e(8)]   (nt = n/16, k = ks*32 + q*8 + e)
//   W1   : [l][nt(64)][ks(4)][lane][e]
//   W2   : [l][nt(8)][kt(32)][lane][e]
__global__ __launch_bounds__(256) void prep_weights(
    const float* __restrict__ Wq, const float* __restrict__ Wk,
    const float* __restrict__ Wv, const float* __restrict__ Wo,
    const float* __restrict__ W1, const float* __restrict__ W2,
    unsigned short* __restrict__ WswQ, unsigned short* __restrict__ WswK,
    unsigned short* __restrict__ WswV, unsigned short* __restrict__ WswO,
    unsigned short* __restrict__ Wsw1, unsigned short* __restrict__ Wsw2,
    float* __restrict__ PEt)
{
    int i = blockIdx.x * 256 + threadIdx.x;
    if (i < 2048) {  // PE table [16][128]
        int s = i >> 7, c = i & 127;
        float expo = (float)((c >> 1) * 2) * (1.0f / 128.0f);
        float denom = powf(10000.0f, expo);
        float ang = (float)s / denom;
        PEt[i] = (c & 1) ? cosf(ang) : sinf(ang);
    }
    if (i < 2 * 16384) {   // QKVO, dst-driven
        int l = i >> 14, r = i & 16383;
        int nt = r >> 11, ks = (r >> 9) & 3, lane = (r >> 3) & 63, e = r & 7;
        int k = ks * 32 + (lane >> 4) * 8 + e;
        int n = nt * 16 + (lane & 15);
        int s = l * 16384 + k * 128 + n;
        WswQ[i] = f2b(Wq[s]); WswK[i] = f2b(Wk[s]);
        WswV[i] = f2b(Wv[s]); WswO[i] = f2b(Wo[s]);
    }
    {   // W1: src [l][k=128][n=1024]
        int l = i >> 17, r = i & 131071;
        int nt = r >> 11, ks = (r >> 9) & 3, lane = (r >> 3) & 63, e = r & 7;
        int k = ks * 32 + (lane >> 4) * 8 + e;
        int n = nt * 16 + (lane & 15);
        Wsw1[i] = f2b(W1[l * 131072 + k * 1024 + n]);
    }
    {   // W2: src [l][k=1024][n=128]
        int l = i >> 17, r = i & 131071;
        int nt = r >> 14, kt = (r >> 9) & 31, lane = (r >> 3) & 63, e = r & 7;
        int k = kt * 32 + (lane >> 4) * 8 + e;
        int n = nt * 16 + (lane & 15);
        Wsw2[i] = f2b(W2[l * 131072 + k * 128 + n]);
    }
}

// Block = 4 waves = 4 batch elements (64 rows). Waves split N (2 n-tiles each).
// Attention is MFMA-based and wave-local (wave w owns element w's 8 heads).
__global__ __launch_bounds__(256, 2) void encoder_fused(
    const float* __restrict__ x, const float* __restrict__ gcn,
    const float* __restrict__ bq, const float* __restrict__ bk,
    const float* __restrict__ bv, const float* __restrict__ bo,
    const float* __restrict__ ln1g, const float* __restrict__ ln1b,
    const float* __restrict__ b1, const float* __restrict__ b2p,
    const float* __restrict__ ln2g, const float* __restrict__ ln2b,
    const float* __restrict__ Wf,
    const unsigned short* __restrict__ WswQ, const unsigned short* __restrict__ WswK,
    const unsigned short* __restrict__ WswV, const unsigned short* __restrict__ WswO,
    const unsigned short* __restrict__ Wsw1, const unsigned short* __restrict__ Wsw2,
    const float* __restrict__ PEt,
    float* __restrict__ acc1)
{
    __shared__ unsigned short ACT[64][STRD];  // activations / LN2 output
    __shared__ unsigned short Qb[64][STRD];   // Q -> ctx -> FF1 chunk (even)
    __shared__ unsigned short Kb[64][STRD];   // K -> H (post-LN1)
    __shared__ unsigned short Vb[64][STRD];   // V^T (per-head) -> FF1 chunk (odd)
    __shared__ float LNp[64][4][2];           // per-row per-wave (sum, sumsq)
    __shared__ float LNs[64][2];              // per-row (mean, inv)
    __shared__ unsigned short Pb[4][16][16];  // per-wave P tile (softmax probs)

    unsigned short* Vb4 = &Vb[0][0];          // V^T alias: [E(4)][g(8)][dh(16)][uk(16)]

    const int t = threadIdx.x;
    const int w = t >> 6, lane = t & 63;
    const int q = lane >> 4, ln = lane & 15;
    const int bbase = blockIdx.x * G_B;

    // ---- load x + PE -> ACT (bf16) ----
    {
        const float4* xb = (const float4*)(x + (size_t)bbase * 2048);
        const float4* pe4 = (const float4*)PEt;
#pragma unroll
        for (int i = 0; i < 8; ++i) {
            int f4 = i * 256 + t;                  // 0..2047
            float4 xv = xb[f4];
            float4 pv = pe4[f4 & 511];
            int flat = f4 * 4;
            int row = flat >> 7, col = flat & 127;
            ushort4 pk = {f2b(xv.x + pv.x), f2b(xv.y + pv.y),
                          f2b(xv.z + pv.z), f2b(xv.w + pv.w)};
            *(ushort4*)&ACT[row][col] = pk;
        }
    }
    __syncthreads();

    for (int l = 0; l < 2; ++l) {
        // ================= QKV =================
        {
            bh8 afr[4][4];
#pragma unroll
            for (int mt = 0; mt < 4; ++mt)
#pragma unroll
                for (int ks = 0; ks < 4; ++ks)
                    afr[mt][ks] = *(const bh8*)&ACT[mt * 16 + ln][ks * 32 + q * 8];
            const unsigned short* Wm[3] = {WswQ + l * 16384, WswK + l * 16384, WswV + l * 16384};
            const float* bias3[3] = {bq + l * 128, bk + l * 128, bv + l * 128};
#pragma unroll
            for (int mtx = 0; mtx < 3; ++mtx) {
#pragma unroll
                for (int i2 = 0; i2 < 2; ++i2) {
                    int nt = w * 2 + i2;
                    bh8 wfr[4];
#pragma unroll
                    for (int ks = 0; ks < 4; ++ks)
                        wfr[ks] = *(const bh8*)(Wm[mtx] + ((nt * 4 + ks) * 64 + lane) * 8);
                    int n = nt * 16 + ln;
                    float bb = bias3[mtx][n];
#pragma unroll
                    for (int mt = 0; mt < 4; ++mt) {
                        fx4 acc = {0.f, 0.f, 0.f, 0.f};
#pragma unroll
                        for (int ks = 0; ks < 4; ++ks) acc = mfma16(afr[mt][ks], wfr[ks], acc);
                        if (mtx == 0) {
#pragma unroll
                            for (int r2 = 0; r2 < 4; ++r2)
                                Qb[mt * 16 + q * 4 + r2][n] = f2b(acc[r2] + bb);
                        } else if (mtx == 1) {
#pragma unroll
                            for (int r2 = 0; r2 < 4; ++r2)
                                Kb[mt * 16 + q * 4 + r2][n] = f2b(acc[r2] + bb);
                        } else {
                            // V stored transposed per head: Vt[E][g][dh][uk]
                            // (s,d) -> g=s>>1, uk=((s&1)<<3)|(d>>4), dh=d&15 (=ln)
#pragma unroll
                            for (int r2 = 0; r2 < 4; ++r2) {
                                int s = q * 4 + r2;
                                Vb4[(((mt * 8 + (s >> 1)) * 16) + ln) * 16 +
                                    (((s & 1) << 3) | nt)] = f2b(acc[r2] + bb);
                            }
                        }
                    }
                }
            }
        }
        __syncthreads();

        // ===== attention, MFMA-based, wave-local: wave w owns element w =====
        // S^T = mfma(A=K, B=Q) (K=32, dh>=16 zero) -> softmax over rows (u_k)
        // ctx^T = mfma(A=V^T, B=P) -> write to Qb at raw-reshape positions.
        {
            const int E = w;
            const int rbase = E * 16 + (ln >> 3);   // + 2g per head
            const int ccol = (ln & 7) * 16;
#pragma unroll
            for (int g = 0; g < 8; ++g) {
                bh8 kfr = 0, qfr = 0;
                if (q < 2) {
                    kfr = *(const bh8*)&Kb[rbase + 2 * g][ccol + q * 8];
                    qfr = *(const bh8*)&Qb[rbase + 2 * g][ccol + q * 8];
                }
                fx4 st = mfma16(kfr, qfr, fx4{0.f, 0.f, 0.f, 0.f});
                float p0 = st[0] * 0.25f, p1 = st[1] * 0.25f;
                float p2 = st[2] * 0.25f, p3 = st[3] * 0.25f;
                float mx = fmaxf(fmaxf(p0, p1), fmaxf(p2, p3));
                mx = fmaxf(mx, __shfl_xor(mx, 16));
                mx = fmaxf(mx, __shfl_xor(mx, 32));
                p0 = __expf(p0 - mx); p1 = __expf(p1 - mx);
                p2 = __expf(p2 - mx); p3 = __expf(p3 - mx);
                float sm = (p0 + p1) + (p2 + p3);
                sm += __shfl_xor(sm, 16);
                sm += __shfl_xor(sm, 32);
                float is = 1.0f / sm;
                ushort4 pk = {f2b(p0 * is), f2b(p1 * is), f2b(p2 * is), f2b(p3 * is)};
                *(ushort4*)&Pb[w][ln][q * 4] = pk;   // Pb[u_q][u_k]=P[u_q][u_k]
                bh8 vfr = 0, pfr = 0;
                if (q < 2) {
                    vfr = *(const bh8*)&Vb4[(((E * 8 + g) * 16) + ln) * 16 + q * 8];
                    pfr = *(const bh8*)&Pb[w][ln][q * 8];
                }
                fx4 cx = mfma16(vfr, pfr, fx4{0.f, 0.f, 0.f, 0.f});
                // cx: rows dh=q*4+r, col u_q=ln -> Qb[E*16+2g+(u_q>>3)][(u_q&7)*16+dh]
                ushort4 ck = {f2b(cx[0]), f2b(cx[1]), f2b(cx[2]), f2b(cx[3])};
                *(ushort4*)&Qb[rbase + 2 * g][ccol + q * 4] = ck;
            }
        }
        __syncthreads();

        // ================= O-proj + residual + LN1 -> Kb (H) ================
        fx4 Cv[2][4];
        {
            bh8 cfr[4][4];
#pragma unroll
            for (int mt = 0; mt < 4; ++mt)
#pragma unroll
                for (int ks = 0; ks < 4; ++ks)
                    cfr[mt][ks] = *(const bh8*)&Qb[mt * 16 + ln][ks * 32 + q * 8];
#pragma unroll
            for (int i2 = 0; i2 < 2; ++i2) {
                int nt = w * 2 + i2, n = nt * 16 + ln;
                bh8 wfr[4];
#pragma unroll
                for (int ks = 0; ks < 4; ++ks)
                    wfr[ks] = *(const bh8*)(WswO + l * 16384 + ((nt * 4 + ks) * 64 + lane) * 8);
                float bb = bo[l * 128 + n];
#pragma unroll
                for (int mt = 0; mt < 4; ++mt) {
                    fx4 acc = {0.f, 0.f, 0.f, 0.f};
#pragma unroll
                    for (int ks = 0; ks < 4; ++ks) acc = mfma16(cfr[mt][ks], wfr[ks], acc);
#pragma unroll
                    for (int r2 = 0; r2 < 4; ++r2)
                        Cv[i2][mt][r2] = acc[r2] + bb +
                            bu2f(ACT[mt * 16 + q * 4 + r2][n]);
                }
            }
        }
        // LN1 partials
#pragma unroll
        for (int mt = 0; mt < 4; ++mt) {
            float s4[4], v4[4];
#pragma unroll
            for (int r2 = 0; r2 < 4; ++r2) {
                float a0 = Cv[0][mt][r2], a1 = Cv[1][mt][r2];
                float s = a0 + a1, v = a0 * a0 + a1 * a1;
#pragma unroll
                for (int m = 1; m < 16; m <<= 1) { s += __shfl_xor(s, m); v += __shfl_xor(v, m); }
                s4[r2] = s; v4[r2] = v;
            }
            if (ln < 8)
                LNp[mt * 16 + q * 4 + (ln >> 1)][w][ln & 1] = (ln & 1) ? v4[ln >> 1] : s4[ln >> 1];
        }
        __syncthreads();
        if (t < 64) {
            float s = LNp[t][0][0] + LNp[t][1][0] + LNp[t][2][0] + LNp[t][3][0];
            float v = LNp[t][0][1] + LNp[t][1][1] + LNp[t][2][1] + LNp[t][3][1];
            float mean = s * (1.0f / 128.0f);
            LNs[t][0] = mean;
            LNs[t][1] = rsqrtf(v * (1.0f / 128.0f) - mean * mean + 1e-5f);
        }
        __syncthreads();
#pragma unroll
        for (int i2 = 0; i2 < 2; ++i2) {
            int n = (w * 2 + i2) * 16 + ln;
            float gg = ln1g[l * 128 + n], be = ln1b[l * 128 + n];
#pragma unroll
            for (int mt = 0; mt < 4; ++mt)
#pragma unroll
                for (int r2 = 0; r2 < 4; ++r2) {
                    int row = mt * 16 + q * 4 + r2;
                    Kb[row][n] = f2b((Cv[i2][mt][r2] - LNs[row][0]) * LNs[row][1] * gg + be);
                }
        }
        __syncthreads();

        // ================= FF (8 chunks of 128 hidden) ======================
        // H fragments hoisted; FF1 chunks ping-pong Qb/Vb (both dead now):
        // ONE barrier per chunk (write->read); WAR at ch+2 covered by ch+1's
        // barrier (waitcnts drain before s_barrier).
        bh8 hfr[4][4];
#pragma unroll
        for (int mt = 0; mt < 4; ++mt)
#pragma unroll
            for (int ks = 0; ks < 4; ++ks)
                hfr[mt][ks] = *(const bh8*)&Kb[mt * 16 + ln][ks * 32 + q * 8];
        fx4 f2a[2][4];
#pragma unroll
        for (int i2 = 0; i2 < 2; ++i2)
#pragma unroll
            for (int mt = 0; mt < 4; ++mt) f2a[i2][mt] = fx4{0.f, 0.f, 0.f, 0.f};
        for (int ch = 0; ch < 8; ++ch) {
            unsigned short (*dst)[STRD] = (ch & 1) ? Vb : Qb;
            bh8 w1fr[2][4];
#pragma unroll
            for (int i2 = 0; i2 < 2; ++i2) {
                int ntg = ch * 8 + w * 2 + i2;
#pragma unroll
                for (int ks = 0; ks < 4; ++ks)
                    w1fr[i2][ks] = *(const bh8*)(Wsw1 + l * 131072 + ((ntg * 4 + ks) * 64 + lane) * 8);
            }
#pragma unroll
            for (int mt = 0; mt < 4; ++mt) {
#pragma unroll
                for (int i2 = 0; i2 < 2; ++i2) {
                    fx4 acc = {0.f, 0.f, 0.f, 0.f};
#pragma unroll
                    for (int ks = 0; ks < 4; ++ks) acc = mfma16(hfr[mt][ks], w1fr[i2][ks], acc);
                    int nl = (w * 2 + i2) * 16 + ln;
                    float bb = b1[l * HID_SZ + ch * 128 + nl];
#pragma unroll
                    for (int r2 = 0; r2 < 4; ++r2) {
                        float vv = acc[r2] + bb;
                        dst[mt * 16 + q * 4 + r2][nl] = f2b(vv > 0.f ? vv : 0.f);
                    }
                }
            }
            __syncthreads();
            bh8 w2fr[2][4];
#pragma unroll
            for (int i2 = 0; i2 < 2; ++i2)
#pragma unroll
                for (int ks = 0; ks < 4; ++ks)
                    w2fr[i2][ks] = *(const bh8*)(Wsw2 + l * 131072 +
                        (((w * 2 + i2) * 32 + ch * 4 + ks) * 64 + lane) * 8);
#pragma unroll
            for (int mt = 0; mt < 4; ++mt) {
                bh8 ffr[4];
#pragma unroll
                for (int ks = 0; ks < 4; ++ks)
                    ffr[ks] = *(const bh8*)&dst[mt * 16 + ln][ks * 32 + q * 8];
#pragma unroll
                for (int i2 = 0; i2 < 2; ++i2)
#pragma unroll
                    for (int ks = 0; ks < 4; ++ks)
                        f2a[i2][mt] = mfma16(ffr[ks], w2fr[i2][ks], f2a[i2][mt]);
            }
            // no trailing barrier: ping-pong buffered
        }
        // epilogue: + b2 + H residual, LN2 -> ACT
        fx4 Cv2[2][4];
#pragma unroll
        for (int i2 = 0; i2 < 2; ++i2) {
            int n = (w * 2 + i2) * 16 + ln;
            float bb = b2p[l * 128 + n];
#pragma unroll
            for (int mt = 0; mt < 4; ++mt)
#pragma unroll
                for (int r2 = 0; r2 < 4; ++r2)
                    Cv2[i2][mt][r2] = f2a[i2][mt][r2] + bb +
                        bu2f(Kb[mt * 16 + q * 4 + r2][n]);
        }
#pragma unroll
        for (int mt = 0; mt < 4; ++mt) {
            float s4[4], v4[4];
#pragma unroll
            for (int r2 = 0; r2 < 4; ++r2) {
                float a0 = Cv2[0][mt][r2], a1 = Cv2[1][mt][r2];
                float s = a0 + a1, v = a0 * a0 + a1 * a1;
#pragma unroll
                for (int m = 1; m < 16; m <<= 1) { s += __shfl_xor(s, m); v += __shfl_xor(v, m); }
                s4[r2] = s; v4[r2] = v;
            }
            if (ln < 8)
                LNp[mt * 16 + q * 4 + (ln >> 1)][w][ln & 1] = (ln & 1) ? v4[ln >> 1] : s4[ln >> 1];
        }
        __syncthreads();
        if (t < 64) {
            float s = LNp[t][0][0] + LNp[t][1][0] + LNp[t][2][0] + LNp[t][3][0];
            float v = LNp[t][0][1] + LNp[t][1][1] + LNp[t][2][1] + LNp[t][3][1];
            float mean = s * (1.0f / 128.0f);
            LNs[t][0] = mean;
            LNs[t][1] = rsqrtf(v * (1.0f / 128.0f) - mean * mean + 1e-5f);
        }
        __syncthreads();
#pragma unroll
        for (int i2 = 0; i2 < 2; ++i2) {
            int n = (w * 2 + i2) * 16 + ln;
            float gg = ln2g[l * 128 + n], be = ln2b[l * 128 + n];
#pragma unroll
            for (int mt = 0; mt < 4; ++mt)
#pragma unroll
                for (int r2 = 0; r2 < 4; ++r2) {
                    int row = mt * 16 + q * 4 + r2;
                    ACT[row][n] = f2b((Cv2[i2][mt][r2] - LNs[row][0]) * LNs[row][1] * gg + be);
                }
        }
        __syncthreads();
    }

    // ============ head partial dot: wave w handles batch bbase + w =========
    {
        int bg = bbase + w;
        float part = 0.f;
        int srow = lane >> 2, c0 = (lane & 3) * 32;
#pragma unroll
        for (int i = 0; i < 4; ++i) {
            bh8 av = *(const bh8*)&ACT[w * 16 + srow][c0 + i * 8];
            int fl = srow * 128 + c0 + i * 8;
#pragma unroll
            for (int e = 0; e < 8; ++e)
                part = fmaf(bu2f((unsigned short)av[e]), Wf[fl + e], part);
        }
        if (lane < GCN_SZ)
            part = fmaf(gcn[(size_t)bg * GCN_SZ + lane], Wf[2048 + lane], part);
#pragma unroll
        for (int off = 32; off; off >>= 1) part += __shfl_xor(part, off);
        if (lane == 0) acc1[bg] = part;
    }
}

// BN batch statistics: per-column sum / sumsq of n = num @ Wn + bnum.
// Also stores n to workspace (if it fits) so the final pass needn't recompute.
__global__ __launch_bounds__(256) void num_stats_kernel(
    const float* __restrict__ num, const float* __restrict__ Wn,
    const float* __restrict__ bnum,
    float* __restrict__ ssum, float* __restrict__ ssq,
    float* __restrict__ nws, int have_nws)
{
    __shared__ float NUM[16][NUMF_SZ + 1];
    __shared__ float cred[4][128];
    const int t = threadIdx.x;
    const int b0 = blockIdx.x * 16;
    const int j = t & 127, sg = t >> 7, s0 = sg * 8;

    for (int idx = t; idx < 16 * NUMF_SZ; idx += 256) {
        int r = idx / NUMF_SZ, f = idx - r * NUMF_SZ;
        NUM[r][f] = num[(size_t)(b0 + r) * NUMF_SZ + f];
    }
    __syncthreads();

    float acc[8];
    float bnv = bnum[j];
#pragma unroll
    for (int r = 0; r < 8; ++r) acc[r] = bnv;
    for (int f = 0; f < NUMF_SZ; ++f) {
        float w = Wn[f * 128 + j];
#pragma unroll
        for (int r = 0; r < 8; ++r) acc[r] = fmaf(NUM[s0 + r][f], w, acc[r]);
    }
    if (have_nws) {
#pragma unroll
        for (int r = 0; r < 8; ++r)
            nws[(size_t)(b0 + s0 + r) * 128 + j] = acc[r];
    }
    float lsum = 0.f, lsq = 0.f;
#pragma unroll
    for (int r = 0; r < 8; ++r) {
        lsum += acc[r];
        lsq = fmaf(acc[r], acc[r], lsq);
    }
    cred[sg][j] = lsum;
    cred[2 + sg][j] = lsq;
    __syncthreads();
    if (sg == 0) atomicAdd(&ssum[j], cred[0][j] + cred[1][j]);
    else         atomicAdd(&ssq[j],  cred[2][j] + cred[3][j]);
}

// Collapse BN into per-column coefficients + scalar:
//   n_bn . Wf3 = sum_j n_j * c_j + C0
__global__ __launch_bounds__(128) void bn_coef_kernel(
    const float* __restrict__ ssum, const float* __restrict__ ssq,
    const float* __restrict__ gamma, const float* __restrict__ beta,
    const float* __restrict__ Wf, const float* __restrict__ bfin,
    float* __restrict__ cvec)
{
    const int j = threadIdx.x;
    __shared__ float red2[2];
    float mean = ssum[j] * (1.0f / (float)B_SZ);
    float var = ssq[j] * (1.0f / (float)B_SZ) - mean * mean;
    float inv = rsqrtf(var + 1e-5f);
    float wj = Wf[2088 + j];
    float gi = gamma[j] * inv;
    cvec[j] = gi * wj;
    float k = (beta[j] - mean * gi) * wj;
#pragma unroll
    for (int o = 32; o; o >>= 1) k += __shfl_down(k, o);
    if ((j & 63) == 0) red2[j >> 6] = k;
    __syncthreads();
    if (j == 0) cvec[128] = red2[0] + red2[1] + bfin[0];
}

// One wave per batch row: dot(nws[b], c) + acc1[b] + C0 -> sigmoid.
__global__ __launch_bounds__(256) void final_fast(
    const float* __restrict__ nws, const float* __restrict__ cvec,
    const float* __restrict__ acc1, float* __restrict__ out)
{
    __shared__ float cs[129];
    const int t = threadIdx.x;
    if (t < 129) cs[t] = cvec[t];
    __syncthreads();
    const int w = t >> 6, lane = t & 63;
    const int b = blockIdx.x * 4 + w;
    const float2* nb = (const float2*)(nws + (size_t)b * 128);
    float2 v = nb[lane];
    float d = v.x * cs[2 * lane] + v.y * cs[2 * lane + 1];
#pragma unroll
    for (int o = 32; o; o >>= 1) d += __shfl_xor(d, o);
    if (lane == 0)
        out[b] = 1.0f / (1.0f + __expf(-(acc1[b] + d + cs[128])));
}

// Fallback (no nws space): recompute n[b], BN, final dot + sigmoid.
__global__ __launch_bounds__(128) void final_kernel(
    const float* __restrict__ num, const float* __restrict__ Wn,
    const float* __restrict__ bnum,
    const float* __restrict__ ssum, const float* __restrict__ ssq,
    const float* __restrict__ gamma, const float* __restrict__ beta,
    const float* __restrict__ Wf, const float* __restrict__ bfin,
    const float* __restrict__ acc1, float* __restrict__ out)
{
    const int b = blockIdx.x, jj = threadIdx.x;
    __shared__ float red2[2];
    __shared__ float NUMr[NUMF_SZ];
    if (jj < NUMF_SZ) NUMr[jj] = num[(size_t)b * NUMF_SZ + jj];
    __syncthreads();
    float nv = bnum[jj];
    for (int f = 0; f < NUMF_SZ; ++f)
        nv = fmaf(NUMr[f], Wn[f * 128 + jj], nv);
    float mean = ssum[jj] * (1.0f / (float)B_SZ);
    float var = ssq[jj] * (1.0f / (float)B_SZ) - mean * mean;
    float bnv = (nv - mean) * rsqrtf(var + 1e-5f) * gamma[jj] + beta[jj];
    float v = bnv * Wf[2088 + jj];
#pragma unroll
    for (int o = 32; o; o >>= 1) v += __shfl_down(v, o);
    if ((jj & 63) == 0) red2[jj >> 6] = v;
    __syncthreads();
    if (jj == 0) {
        float z = acc1[b] + red2[0] + red2[1] + bfin[0];
        out[b] = 1.0f / (1.0f + __expf(-z));
    }
}

extern "C" void kernel_launch(void* const* d_in, const int* in_sizes, int n_in,
                              void* d_out, int out_size, void* d_ws, size_t ws_size,
                              hipStream_t stream)
{
    const float* x    = (const float*)d_in[0];
    const float* gcn  = (const float*)d_in[1];
    const float* num  = (const float*)d_in[2];
    const float* Wq   = (const float*)d_in[3];
    const float* bq   = (const float*)d_in[4];
    const float* Wk   = (const float*)d_in[5];
    const float* bk   = (const float*)d_in[6];
    const float* Wv   = (const float*)d_in[7];
    const float* bv   = (const float*)d_in[8];
    const float* Wo   = (const float*)d_in[9];
    const float* bo   = (const float*)d_in[10];
    const float* ln1g = (const float*)d_in[11];
    const float* ln1b = (const float*)d_in[12];
    const float* W1   = (const float*)d_in[13];
    const float* b1   = (const float*)d_in[14];
    const float* W2   = (const float*)d_in[15];
    const float* b2p  = (const float*)d_in[16];
    const float* ln2g = (const float*)d_in[17];
    const float* ln2b = (const float*)d_in[18];
    const float* Wn   = (const float*)d_in[19];
    const float* bnum = (const float*)d_in[20];
    const float* bng  = (const float*)d_in[21];
    const float* bnb  = (const float*)d_in[22];
    const float* Wf   = (const float*)d_in[23];
    const float* bfin = (const float*)d_in[24];

    // ws: acc1 (8192 f32) | ssum | ssq | pad to 40960 | swizzled bf16 weights
    //     | PE (8 KB) | n precompute (4 MB) | cvec (129 f32)
    float* acc1 = (float*)d_ws;
    float* ssum = acc1 + B_SZ;
    float* ssq  = ssum + 128;
    unsigned short* wb = (unsigned short*)((char*)d_ws + 40960);
    unsigned short* WswQ = wb;
    unsigned short* WswK = wb + 32768;
    unsigned short* WswV = wb + 65536;
    unsigned short* WswO = wb + 98304;
    unsigned short* Wsw1 = wb + 131072;
    unsigned short* Wsw2 = wb + 393216;
    float* PEt = (float*)((char*)d_ws + 40960 + 1310720);
    const size_t nws_off = 40960 + 1310720 + 8192;
    float* nws = (float*)((char*)d_ws + nws_off);
    const size_t cvec_off = nws_off + (size_t)B_SZ * 128 * sizeof(float);
    float* cvec = (float*)((char*)d_ws + cvec_off);
    const int have_nws = (ws_size >= cvec_off + 132 * sizeof(float)) ? 1 : 0;

    hipMemsetAsync(ssum, 0, 2 * 128 * sizeof(float), stream);
    prep_weights<<<1024, 256, 0, stream>>>(Wq, Wk, Wv, Wo, W1, W2,
        WswQ, WswK, WswV, WswO, Wsw1, Wsw2, PEt);
    encoder_fused<<<NBLK, 256, 0, stream>>>(x, gcn, bq, bk, bv, bo,
        ln1g, ln1b, b1, b2p, ln2g, ln2b, Wf,
        WswQ, WswK, WswV, WswO, Wsw1, Wsw2, PEt, acc1);
    num_stats_kernel<<<B_SZ / 16, 256, 0, stream>>>(num, Wn, bnum, ssum, ssq,
        nws, have_nws);
    if (have_nws) {
        bn_coef_kernel<<<1, 128, 0, stream>>>(ssum, ssq, bng, bnb, Wf, bfin, cvec);
        final_fast<<<B_SZ / 4, 256, 0, stream>>>(nws, cvec, acc1, (float*)d_out);
    } else {
        final_kernel<<<B_SZ, 128, 0, stream>>>(num, Wn, bnum, ssum, ssq, bng, bnb,
            Wf, bfin, acc1, (float*)d_out);
    }
}

// Round 4
// 402.792 us; speedup vs baseline: 1.3536x; 1.1394x over previous
//
#include <hip/hip_runtime.h>
#include <hip/hip_bf16.h>
#include <math.h>

#define B_SZ   8192
#define S_SZ   16
#define D_SZ   128
#define HID_SZ 1024
#define NUMF_SZ 103
#define GCN_SZ 40
#define G_B    4                 // batch elements per block (64 rows)
#define NBLK   (B_SZ / G_B)      // 2048 blocks
#define STRD   136               // LDS row stride (shorts), pad 8

typedef short bh8 __attribute__((ext_vector_type(8)));   // 8 bf16 (4 VGPRs)
typedef float fx4 __attribute__((ext_vector_type(4)));   // MFMA accumulator
typedef unsigned short us4 __attribute__((ext_vector_type(4))); // 4 bf16 (8B)

__device__ __forceinline__ fx4 mfma16(bh8 a, bh8 b, fx4 c) {
    return __builtin_amdgcn_mfma_f32_16x16x32_bf16(a, b, c, 0, 0, 0);
}

// fp32 -> bf16 bits via native conversion (RNE, 1 VALU op)
__device__ __forceinline__ unsigned short f2b(float f) {
    union { __hip_bfloat16 b; unsigned short u; } cv;
    cv.b = __float2bfloat16(f);
    return cv.u;
}
__device__ __forceinline__ float bu2f(unsigned short u) {
    return __uint_as_float(((unsigned)u) << 16);
}

// Swizzle all weights into B-fragment-linear bf16 order:
//   QKVO : [l][nt(8)][ks(4)][lane(64)][e(8)]   (nt = n/16, k = ks*32 + q*8 + e)
//   W1   : [l][nt(64)][ks(4)][lane][e]
//   W2   : [l][nt(8)][kt(32)][lane][e]
__global__ __launch_bounds__(256) void prep_weights(
    const float* __restrict__ Wq, const float* __restrict__ Wk,
    const float* __restrict__ Wv, const float* __restrict__ Wo,
    const float* __restrict__ W1, const float* __restrict__ W2,
    unsigned short* __restrict__ WswQ, unsigned short* __restrict__ WswK,
    unsigned short* __restrict__ WswV, unsigned short* __restrict__ WswO,
    unsigned short* __restrict__ Wsw1, unsigned short* __restrict__ Wsw2,
    float* __restrict__ PEt)
{
    int i = blockIdx.x * 256 + threadIdx.x;
    if (i < 2048) {  // PE table [16][128]
        int s = i >> 7, c = i & 127;
        float expo = (float)((c >> 1) * 2) * (1.0f / 128.0f);
        float denom = powf(10000.0f, expo);
        float ang = (float)s / denom;
        PEt[i] = (c & 1) ? cosf(ang) : sinf(ang);
    }
    if (i < 2 * 16384) {   // QKVO, dst-driven
        int l = i >> 14, r = i & 16383;
        int nt = r >> 11, ks = (r >> 9) & 3, lane = (r >> 3) & 63, e = r & 7;
        int k = ks * 32 + (lane >> 4) * 8 + e;
        int n = nt * 16 + (lane & 15);
        int s = l * 16384 + k * 128 + n;
        WswQ[i] = f2b(Wq[s]); WswK[i] = f2b(Wk[s]);
        WswV[i] = f2b(Wv[s]); WswO[i] = f2b(Wo[s]);
    }
    {   // W1: src [l][k=128][n=1024]
        int l = i >> 17, r = i & 131071;
        int nt = r >> 11, ks = (r >> 9) & 3, lane = (r >> 3) & 63, e = r & 7;
        int k = ks * 32 + (lane >> 4) * 8 + e;
        int n = nt * 16 + (lane & 15);
        Wsw1[i] = f2b(W1[l * 131072 + k * 1024 + n]);
    }
    {   // W2: src [l][k=1024][n=128]
        int l = i >> 17, r = i & 131071;
        int nt = r >> 14, kt = (r >> 9) & 31, lane = (r >> 3) & 63, e = r & 7;
        int k = kt * 32 + (lane >> 4) * 8 + e;
        int n = nt * 16 + (lane & 15);
        Wsw2[i] = f2b(W2[l * 131072 + k * 128 + n]);
    }
}

// Block = 4 waves = 4 batch elements (64 rows). Waves split N (2 n-tiles each).
// GEMMs use SWAPPED operand order: mfma(A=W, B=act) -> C^T, so each lane holds
// 4 consecutive output COLUMNS at one row -> ushort4 packed LDS stores and
// 2-shuffle LN reductions (vs 4x ds_write_b16 + 8-shuffle before).
__global__ __launch_bounds__(256, 2) void encoder_fused(
    const float* __restrict__ x, const float* __restrict__ gcn,
    const float* __restrict__ bq, const float* __restrict__ bk,
    const float* __restrict__ bv, const float* __restrict__ bo,
    const float* __restrict__ ln1g, const float* __restrict__ ln1b,
    const float* __restrict__ b1, const float* __restrict__ b2p,
    const float* __restrict__ ln2g, const float* __restrict__ ln2b,
    const float* __restrict__ Wf,
    const unsigned short* __restrict__ WswQ, const unsigned short* __restrict__ WswK,
    const unsigned short* __restrict__ WswV, const unsigned short* __restrict__ WswO,
    const unsigned short* __restrict__ Wsw1, const unsigned short* __restrict__ Wsw2,
    const float* __restrict__ PEt,
    float* __restrict__ acc1)
{
    __shared__ unsigned short ACT[64][STRD];  // activations / LN2 output
    __shared__ unsigned short Qb[64][STRD];   // Q -> ctx -> FF1 chunk (even)
    __shared__ unsigned short Kb[64][STRD];   // K -> H (post-LN1)
    __shared__ unsigned short Vb[64][STRD];   // V^T (per-head) -> FF1 chunk (odd)
    __shared__ float2 LNp2[64][4];            // per-row per-wave (sum, sumsq)
    __shared__ float LNs[64][2];              // per-row (mean, inv)
    __shared__ unsigned short Pb[4][16][16];  // per-wave P tile (softmax probs)

    unsigned short* Vb4 = &Vb[0][0];          // V^T alias: [E(4)][g(8)][dh(16)][uk(16)]

    const int t = threadIdx.x;
    const int w = t >> 6, lane = t & 63;
    const int q = lane >> 4, ln = lane & 15;
    const int bbase = blockIdx.x * G_B;

    // ---- load x + PE -> ACT (bf16) ----
    {
        const float4* xb = (const float4*)(x + (size_t)bbase * 2048);
        const float4* pe4 = (const float4*)PEt;
#pragma unroll
        for (int i = 0; i < 8; ++i) {
            int f4 = i * 256 + t;                  // 0..2047
            float4 xv = xb[f4];
            float4 pv = pe4[f4 & 511];
            int flat = f4 * 4;
            int row = flat >> 7, col = flat & 127;
            ushort4 pk = {f2b(xv.x + pv.x), f2b(xv.y + pv.y),
                          f2b(xv.z + pv.z), f2b(xv.w + pv.w)};
            *(ushort4*)&ACT[row][col] = pk;
        }
    }
    __syncthreads();

    for (int l = 0; l < 2; ++l) {
        // ================= QKV =================
        {
            bh8 afr[4][4];
#pragma unroll
            for (int mt = 0; mt < 4; ++mt)
#pragma unroll
                for (int ks = 0; ks < 4; ++ks)
                    afr[mt][ks] = *(const bh8*)&ACT[mt * 16 + ln][ks * 32 + q * 8];
            // ---- Q and K: swapped-C, packed ushort4 stores ----
#pragma unroll
            for (int mtx = 0; mtx < 2; ++mtx) {
                const unsigned short* Wm = (mtx == 0) ? WswQ + l * 16384 : WswK + l * 16384;
                const float* bias = (mtx == 0) ? bq + l * 128 : bk + l * 128;
                unsigned short (*dst)[STRD] = (mtx == 0) ? Qb : Kb;
#pragma unroll
                for (int i2 = 0; i2 < 2; ++i2) {
                    int nt = w * 2 + i2;
                    bh8 wfr[4];
#pragma unroll
                    for (int ks = 0; ks < 4; ++ks)
                        wfr[ks] = *(const bh8*)(Wm + ((nt * 4 + ks) * 64 + lane) * 8);
                    int n0 = nt * 16 + q * 4;
                    fx4 bb4 = *(const fx4*)&bias[n0];
#pragma unroll
                    for (int mt = 0; mt < 4; ++mt) {
                        fx4 acc = {0.f, 0.f, 0.f, 0.f};
#pragma unroll
                        for (int ks = 0; ks < 4; ++ks) acc = mfma16(wfr[ks], afr[mt][ks], acc);
                        us4 o;
#pragma unroll
                        for (int r2 = 0; r2 < 4; ++r2) o[r2] = f2b(acc[r2] + bb4[r2]);
                        *(us4*)&dst[mt * 16 + ln][n0] = o;
                    }
                }
            }
            // ---- V: normal-C orientation, scattered into V^T layout ----
#pragma unroll
            for (int i2 = 0; i2 < 2; ++i2) {
                int nt = w * 2 + i2;
                bh8 wfr[4];
#pragma unroll
                for (int ks = 0; ks < 4; ++ks)
                    wfr[ks] = *(const bh8*)(WswV + l * 16384 + ((nt * 4 + ks) * 64 + lane) * 8);
                int n = nt * 16 + ln;
                float bb = bv[l * 128 + n];
#pragma unroll
                for (int mt = 0; mt < 4; ++mt) {
                    fx4 acc = {0.f, 0.f, 0.f, 0.f};
#pragma unroll
                    for (int ks = 0; ks < 4; ++ks) acc = mfma16(afr[mt][ks], wfr[ks], acc);
                    // Vt[E][g][dh][uk]: (s,d) -> g=s>>1, uk=((s&1)<<3)|nt, dh=ln
#pragma unroll
                    for (int r2 = 0; r2 < 4; ++r2) {
                        int s = q * 4 + r2;
                        Vb4[(((mt * 8 + (s >> 1)) * 16) + ln) * 16 +
                            (((s & 1) << 3) | nt)] = f2b(acc[r2] + bb);
                    }
                }
            }
        }
        __syncthreads();

        // ===== attention, MFMA-based, wave-local: wave w owns element w =====
        // S^T = mfma(A=K, B=Q) (K=32, dh>=16 zero) -> softmax over rows (u_k)
        // ctx^T = mfma(A=V^T, B=P) -> write to Qb at raw-reshape positions.
        {
            const int E = w;
            const int rbase = E * 16 + (ln >> 3);   // + 2g per head
            const int ccol = (ln & 7) * 16;
#pragma unroll
            for (int g = 0; g < 8; ++g) {
                bh8 kfr = 0, qfr = 0;
                if (q < 2) {
                    kfr = *(const bh8*)&Kb[rbase + 2 * g][ccol + q * 8];
                    qfr = *(const bh8*)&Qb[rbase + 2 * g][ccol + q * 8];
                }
                fx4 st = mfma16(kfr, qfr, fx4{0.f, 0.f, 0.f, 0.f});
                float p0 = st[0] * 0.25f, p1 = st[1] * 0.25f;
                float p2 = st[2] * 0.25f, p3 = st[3] * 0.25f;
                float mx = fmaxf(fmaxf(p0, p1), fmaxf(p2, p3));
                mx = fmaxf(mx, __shfl_xor(mx, 16));
                mx = fmaxf(mx, __shfl_xor(mx, 32));
                p0 = __expf(p0 - mx); p1 = __expf(p1 - mx);
                p2 = __expf(p2 - mx); p3 = __expf(p3 - mx);
                float sm = (p0 + p1) + (p2 + p3);
                sm += __shfl_xor(sm, 16);
                sm += __shfl_xor(sm, 32);
                float is = 1.0f / sm;
                ushort4 pk = {f2b(p0 * is), f2b(p1 * is), f2b(p2 * is), f2b(p3 * is)};
                *(ushort4*)&Pb[w][ln][q * 4] = pk;   // Pb[u_q][u_k]=P[u_q][u_k]
                bh8 vfr = 0, pfr = 0;
                if (q < 2) {
                    vfr = *(const bh8*)&Vb4[(((E * 8 + g) * 16) + ln) * 16 + q * 8];
                    pfr = *(const bh8*)&Pb[w][ln][q * 8];
                }
                fx4 cx = mfma16(vfr, pfr, fx4{0.f, 0.f, 0.f, 0.f});
                // cx: rows dh=q*4+r, col u_q=ln -> Qb[E*16+2g+(u_q>>3)][(u_q&7)*16+dh]
                ushort4 ck = {f2b(cx[0]), f2b(cx[1]), f2b(cx[2]), f2b(cx[3])};
                *(ushort4*)&Qb[rbase + 2 * g][ccol + q * 4] = ck;
            }
        }
        __syncthreads();

        // ========= O-proj (swapped-C) + residual + LN1 -> Kb (H) ===========
        fx4 Cv[2][4];
        {
            bh8 cfr[4][4];
#pragma unroll
            for (int mt = 0; mt < 4; ++mt)
#pragma unroll
                for (int ks = 0; ks < 4; ++ks)
                    cfr[mt][ks] = *(const bh8*)&Qb[mt * 16 + ln][ks * 32 + q * 8];
#pragma unroll
            for (int i2 = 0; i2 < 2; ++i2) {
                int nt = w * 2 + i2, n0 = nt * 16 + q * 4;
                bh8 wfr[4];
#pragma unroll
                for (int ks = 0; ks < 4; ++ks)
                    wfr[ks] = *(const bh8*)(WswO + l * 16384 + ((nt * 4 + ks) * 64 + lane) * 8);
                fx4 bb4 = *(const fx4*)&bo[l * 128 + n0];
#pragma unroll
                for (int mt = 0; mt < 4; ++mt) {
                    fx4 acc = {0.f, 0.f, 0.f, 0.f};
#pragma unroll
                    for (int ks = 0; ks < 4; ++ks) acc = mfma16(wfr[ks], cfr[mt][ks], acc);
                    us4 rv = *(const us4*)&ACT[mt * 16 + ln][n0];
#pragma unroll
                    for (int r2 = 0; r2 < 4; ++r2)
                        Cv[i2][mt][r2] = acc[r2] + bb4[r2] + bu2f(rv[r2]);
                }
            }
        }
        // LN1 partials: lane holds 8 values of row mt*16+ln -> 2 shuffles
#pragma unroll
        for (int mt = 0; mt < 4; ++mt) {
            float s = 0.f, v = 0.f;
#pragma unroll
            for (int i2 = 0; i2 < 2; ++i2)
#pragma unroll
                for (int r2 = 0; r2 < 4; ++r2) {
                    float a = Cv[i2][mt][r2];
                    s += a; v = fmaf(a, a, v);
                }
            s += __shfl_xor(s, 16); v += __shfl_xor(v, 16);
            s += __shfl_xor(s, 32); v += __shfl_xor(v, 32);
            if (lane < 16) LNp2[mt * 16 + ln][w] = float2{s, v};
        }
        __syncthreads();
        if (t < 64) {
            float2 a0 = LNp2[t][0], a1 = LNp2[t][1];
            float2 a2 = LNp2[t][2], a3 = LNp2[t][3];
            float s = (a0.x + a1.x) + (a2.x + a3.x);
            float v = (a0.y + a1.y) + (a2.y + a3.y);
            float mean = s * (1.0f / 128.0f);
            LNs[t][0] = mean;
            LNs[t][1] = rsqrtf(v * (1.0f / 128.0f) - mean * mean + 1e-5f);
        }
        __syncthreads();
#pragma unroll
        for (int i2 = 0; i2 < 2; ++i2) {
            int n0 = (w * 2 + i2) * 16 + q * 4;
            fx4 gg = *(const fx4*)&ln1g[l * 128 + n0];
            fx4 be = *(const fx4*)&ln1b[l * 128 + n0];
#pragma unroll
            for (int mt = 0; mt < 4; ++mt) {
                int row = mt * 16 + ln;
                float mean = LNs[row][0], inv = LNs[row][1];
                us4 o;
#pragma unroll
                for (int r2 = 0; r2 < 4; ++r2)
                    o[r2] = f2b((Cv[i2][mt][r2] - mean) * inv * gg[r2] + be[r2]);
                *(us4*)&Kb[row][n0] = o;
            }
        }
        __syncthreads();

        // ================= FF (8 chunks of 128 hidden) ======================
        // H fragments hoisted; FF1 chunks ping-pong Qb/Vb: ONE barrier/chunk.
        bh8 hfr[4][4];
#pragma unroll
        for (int mt = 0; mt < 4; ++mt)
#pragma unroll
            for (int ks = 0; ks < 4; ++ks)
                hfr[mt][ks] = *(const bh8*)&Kb[mt * 16 + ln][ks * 32 + q * 8];
        fx4 f2a[2][4];
#pragma unroll
        for (int i2 = 0; i2 < 2; ++i2)
#pragma unroll
            for (int mt = 0; mt < 4; ++mt) f2a[i2][mt] = fx4{0.f, 0.f, 0.f, 0.f};
        for (int ch = 0; ch < 8; ++ch) {
            unsigned short (*dst)[STRD] = (ch & 1) ? Vb : Qb;
            bh8 w1fr[2][4];
#pragma unroll
            for (int i2 = 0; i2 < 2; ++i2) {
                int ntg = ch * 8 + w * 2 + i2;
#pragma unroll
                for (int ks = 0; ks < 4; ++ks)
                    w1fr[i2][ks] = *(const bh8*)(Wsw1 + l * 131072 + ((ntg * 4 + ks) * 64 + lane) * 8);
            }
#pragma unroll
            for (int mt = 0; mt < 4; ++mt) {
#pragma unroll
                for (int i2 = 0; i2 < 2; ++i2) {
                    fx4 acc = {0.f, 0.f, 0.f, 0.f};
#pragma unroll
                    for (int ks = 0; ks < 4; ++ks) acc = mfma16(w1fr[i2][ks], hfr[mt][ks], acc);
                    int nl0 = (w * 2 + i2) * 16 + q * 4;
                    fx4 bb4 = *(const fx4*)&b1[l * HID_SZ + ch * 128 + nl0];
                    us4 o;
#pragma unroll
                    for (int r2 = 0; r2 < 4; ++r2) {
                        float vv = acc[r2] + bb4[r2];
                        o[r2] = f2b(vv > 0.f ? vv : 0.f);
                    }
                    *(us4*)&dst[mt * 16 + ln][nl0] = o;
                }
            }
            __syncthreads();
            bh8 w2fr[2][4];
#pragma unroll
            for (int i2 = 0; i2 < 2; ++i2)
#pragma unroll
                for (int ks = 0; ks < 4; ++ks)
                    w2fr[i2][ks] = *(const bh8*)(Wsw2 + l * 131072 +
                        (((w * 2 + i2) * 32 + ch * 4 + ks) * 64 + lane) * 8);
#pragma unroll
            for (int mt = 0; mt < 4; ++mt) {
                bh8 ffr[4];
#pragma unroll
                for (int ks = 0; ks < 4; ++ks)
                    ffr[ks] = *(const bh8*)&dst[mt * 16 + ln][ks * 32 + q * 8];
#pragma unroll
                for (int i2 = 0; i2 < 2; ++i2)
#pragma unroll
                    for (int ks = 0; ks < 4; ++ks)
                        f2a[i2][mt] = mfma16(w2fr[i2][ks], ffr[ks], f2a[i2][mt]);
            }
            // no trailing barrier: ping-pong buffered
        }
        // epilogue: + b2 + H residual, LN2 -> ACT
        fx4 Cv2[2][4];
#pragma unroll
        for (int i2 = 0; i2 < 2; ++i2) {
            int n0 = (w * 2 + i2) * 16 + q * 4;
            fx4 bb4 = *(const fx4*)&b2p[l * 128 + n0];
#pragma unroll
            for (int mt = 0; mt < 4; ++mt) {
                us4 rv = *(const us4*)&Kb[mt * 16 + ln][n0];
#pragma unroll
                for (int r2 = 0; r2 < 4; ++r2)
                    Cv2[i2][mt][r2] = f2a[i2][mt][r2] + bb4[r2] + bu2f(rv[r2]);
            }
        }
#pragma unroll
        for (int mt = 0; mt < 4; ++mt) {
            float s = 0.f, v = 0.f;
#pragma unroll
            for (int i2 = 0; i2 < 2; ++i2)
#pragma unroll
                for (int r2 = 0; r2 < 4; ++r2) {
                    float a = Cv2[i2][mt][r2];
                    s += a; v = fmaf(a, a, v);
                }
            s += __shfl_xor(s, 16); v += __shfl_xor(v, 16);
            s += __shfl_xor(s, 32); v += __shfl_xor(v, 32);
            if (lane < 16) LNp2[mt * 16 + ln][w] = float2{s, v};
        }
        __syncthreads();
        if (t < 64) {
            float2 a0 = LNp2[t][0], a1 = LNp2[t][1];
            float2 a2 = LNp2[t][2], a3 = LNp2[t][3];
            float s = (a0.x + a1.x) + (a2.x + a3.x);
            float v = (a0.y + a1.y) + (a2.y + a3.y);
            float mean = s * (1.0f / 128.0f);
            LNs[t][0] = mean;
            LNs[t][1] = rsqrtf(v * (1.0f / 128.0f) - mean * mean + 1e-5f);
        }
        __syncthreads();
#pragma unroll
        for (int i2 = 0; i2 < 2; ++i2) {
            int n0 = (w * 2 + i2) * 16 + q * 4;
            fx4 gg = *(const fx4*)&ln2g[l * 128 + n0];
            fx4 be = *(const fx4*)&ln2b[l * 128 + n0];
#pragma unroll
            for (int mt = 0; mt < 4; ++mt) {
                int row = mt * 16 + ln;
                float mean = LNs[row][0], inv = LNs[row][1];
                us4 o;
#pragma unroll
                for (int r2 = 0; r2 < 4; ++r2)
                    o[r2] = f2b((Cv2[i2][mt][r2] - mean) * inv * gg[r2] + be[r2]);
                *(us4*)&ACT[row][n0] = o;
            }
        }
        __syncthreads();
    }

    // ============ head partial dot: wave w handles batch bbase + w =========
    {
        int bg = bbase + w;
        float part = 0.f;
        int srow = lane >> 2, c0 = (lane & 3) * 32;
#pragma unroll
        for (int i = 0; i < 4; ++i) {
            bh8 av = *(const bh8*)&ACT[w * 16 + srow][c0 + i * 8];
            int fl = srow * 128 + c0 + i * 8;
#pragma unroll
            for (int e = 0; e < 8; ++e)
                part = fmaf(bu2f((unsigned short)av[e]), Wf[fl + e], part);
        }
        if (lane < GCN_SZ)
            part = fmaf(gcn[(size_t)bg * GCN_SZ + lane], Wf[2048 + lane], part);
#pragma unroll
        for (int off = 32; off; off >>= 1) part += __shfl_xor(part, off);
        if (lane == 0) acc1[bg] = part;
    }
}

// BN batch statistics: per-column sum / sumsq of n = num @ Wn + bnum.
// Also stores n to workspace (if it fits) so the final pass needn't recompute.
__global__ __launch_bounds__(256) void num_stats_kernel(
    const float* __restrict__ num, const float* __restrict__ Wn,
    const float* __restrict__ bnum,
    float* __restrict__ ssum, float* __restrict__ ssq,
    float* __restrict__ nws, int have_nws)
{
    __shared__ float NUM[16][NUMF_SZ + 1];
    __shared__ float cred[4][128];
    const int t = threadIdx.x;
    const int b0 = blockIdx.x * 16;
    const int j = t & 127, sg = t >> 7, s0 = sg * 8;

    for (int idx = t; idx < 16 * NUMF_SZ; idx += 256) {
        int r = idx / NUMF_SZ, f = idx - r * NUMF_SZ;
        NUM[r][f] = num[(size_t)(b0 + r) * NUMF_SZ + f];
    }
    __syncthreads();

    float acc[8];
    float bnv = bnum[j];
#pragma unroll
    for (int r = 0; r < 8; ++r) acc[r] = bnv;
    for (int f = 0; f < NUMF_SZ; ++f) {
        float w = Wn[f * 128 + j];
#pragma unroll
        for (int r = 0; r < 8; ++r) acc[r] = fmaf(NUM[s0 + r][f], w, acc[r]);
    }
    if (have_nws) {
#pragma unroll
        for (int r = 0; r < 8; ++r)
            nws[(size_t)(b0 + s0 + r) * 128 + j] = acc[r];
    }
    float lsum = 0.f, lsq = 0.f;
#pragma unroll
    for (int r = 0; r < 8; ++r) {
        lsum += acc[r];
        lsq = fmaf(acc[r], acc[r], lsq);
    }
    cred[sg][j] = lsum;
    cred[2 + sg][j] = lsq;
    __syncthreads();
    if (sg == 0) atomicAdd(&ssum[j], cred[0][j] + cred[1][j]);
    else         atomicAdd(&ssq[j],  cred[2][j] + cred[3][j]);
}

// Collapse BN into per-column coefficients + scalar:
//   n_bn . Wf3 = sum_j n_j * c_j + C0
__global__ __launch_bounds__(128) void bn_coef_kernel(
    const float* __restrict__ ssum, const float* __restrict__ ssq,
    const float* __restrict__ gamma, const float* __restrict__ beta,
    const float* __restrict__ Wf, const float* __restrict__ bfin,
    float* __restrict__ cvec)
{
    const int j = threadIdx.x;
    __shared__ float red2[2];
    float mean = ssum[j] * (1.0f / (float)B_SZ);
    float var = ssq[j] * (1.0f / (float)B_SZ) - mean * mean;
    float inv = rsqrtf(var + 1e-5f);
    float wj = Wf[2088 + j];
    float gi = gamma[j] * inv;
    cvec[j] = gi * wj;
    float k = (beta[j] - mean * gi) * wj;
#pragma unroll
    for (int o = 32; o; o >>= 1) k += __shfl_down(k, o);
    if ((j & 63) == 0) red2[j >> 6] = k;
    __syncthreads();
    if (j == 0) cvec[128] = red2[0] + red2[1] + bfin[0];
}

// One wave per batch row: dot(nws[b], c) + acc1[b] + C0 -> sigmoid.
__global__ __launch_bounds__(256) void final_fast(
    const float* __restrict__ nws, const float* __restrict__ cvec,
    const float* __restrict__ acc1, float* __restrict__ out)
{
    __shared__ float cs[129];
    const int t = threadIdx.x;
    if (t < 129) cs[t] = cvec[t];
    __syncthreads();
    const int w = t >> 6, lane = t & 63;
    const int b = blockIdx.x * 4 + w;
    const float2* nb = (const float2*)(nws + (size_t)b * 128);
    float2 v = nb[lane];
    float d = v.x * cs[2 * lane] + v.y * cs[2 * lane + 1];
#pragma unroll
    for (int o = 32; o; o >>= 1) d += __shfl_xor(d, o);
    if (lane == 0)
        out[b] = 1.0f / (1.0f + __expf(-(acc1[b] + d + cs[128])));
}

// Fallback (no nws space): recompute n[b], BN, final dot + sigmoid.
__global__ __launch_bounds__(128) void final_kernel(
    const float* __restrict__ num, const float* __restrict__ Wn,
    const float* __restrict__ bnum,
    const float* __restrict__ ssum, const float* __restrict__ ssq,
    const float* __restrict__ gamma, const float* __restrict__ beta,
    const float* __restrict__ Wf, const float* __restrict__ bfin,
    const float* __restrict__ acc1, float* __restrict__ out)
{
    const int b = blockIdx.x, jj = threadIdx.x;
    __shared__ float red2[2];
    __shared__ float NUMr[NUMF_SZ];
    if (jj < NUMF_SZ) NUMr[jj] = num[(size_t)b * NUMF_SZ + jj];
    __syncthreads();
    float nv = bnum[jj];
    for (int f = 0; f < NUMF_SZ; ++f)
        nv = fmaf(NUMr[f], Wn[f * 128 + jj], nv);
    float mean = ssum[jj] * (1.0f / (float)B_SZ);
    float var = ssq[jj] * (1.0f / (float)B_SZ) - mean * mean;
    float bnv = (nv - mean) * rsqrtf(var + 1e-5f) * gamma[jj] + beta[jj];
    float v = bnv * Wf[2088 + jj];
#pragma unroll
    for (int o = 32; o; o >>= 1) v += __shfl_down(v, o);
    if ((jj & 63) == 0) red2[jj >> 6] = v;
    __syncthreads();
    if (jj == 0) {
        float z = acc1[b] + red2[0] + red2[1] + bfin[0];
        out[b] = 1.0f / (1.0f + __expf(-z));
    }
}

extern "C" void kernel_launch(void* const* d_in, const int* in_sizes, int n_in,
                              void* d_out, int out_size, void* d_ws, size_t ws_size,
                              hipStream_t stream)
{
    const float* x    = (const float*)d_in[0];
    const float* gcn  = (const float*)d_in[1];
    const float* num  = (const float*)d_in[2];
    const float* Wq   = (const float*)d_in[3];
    const float* bq   = (const float*)d_in[4];
    const float* Wk   = (const float*)d_in[5];
    const float* bk   = (const float*)d_in[6];
    const float* Wv   = (const float*)d_in[7];
    const float* bv   = (const float*)d_in[8];
    const float* Wo   = (const float*)d_in[9];
    const float* bo   = (const float*)d_in[10];
    const float* ln1g = (const float*)d_in[11];
    const float* ln1b = (const float*)d_in[12];
    const float* W1   = (const float*)d_in[13];
    const float* b1   = (const float*)d_in[14];
    const float* W2   = (const float*)d_in[15];
    const float* b2p  = (const float*)d_in[16];
    const float* ln2g = (const float*)d_in[17];
    const float* ln2b = (const float*)d_in[18];
    const float* Wn   = (const float*)d_in[19];
    const float* bnum = (const float*)d_in[20];
    const float* bng  = (const float*)d_in[21];
    const float* bnb  = (const float*)d_in[22];
    const float* Wf   = (const float*)d_in[23];
    const float* bfin = (const float*)d_in[24];

    // ws: acc1 (8192 f32) | ssum | ssq | pad to 40960 | swizzled bf16 weights
    //     | PE (8 KB) | n precompute (4 MB) | cvec (129 f32)
    float* acc1 = (float*)d_ws;
    float* ssum = acc1 + B_SZ;
    float* ssq  = ssum + 128;
    unsigned short* wb = (unsigned short*)((char*)d_ws + 40960);
    unsigned short* WswQ = wb;
    unsigned short* WswK = wb + 32768;
    unsigned short* WswV = wb + 65536;
    unsigned short* WswO = wb + 98304;
    unsigned short* Wsw1 = wb + 131072;
    unsigned short* Wsw2 = wb + 393216;
    float* PEt = (float*)((char*)d_ws + 40960 + 1310720);
    const size_t nws_off = 40960 + 1310720 + 8192;
    float* nws = (float*)((char*)d_ws + nws_off);
    const size_t cvec_off = nws_off + (size_t)B_SZ * 128 * sizeof(float);
    float* cvec = (float*)((char*)d_ws + cvec_off);
    const int have_nws = (ws_size >= cvec_off + 132 * sizeof(float)) ? 1 : 0;

    hipMemsetAsync(ssum, 0, 2 * 128 * sizeof(float), stream);
    prep_weights<<<1024, 256, 0, stream>>>(Wq, Wk, Wv, Wo, W1, W2,
        WswQ, WswK, WswV, WswO, Wsw1, Wsw2, PEt);
    encoder_fused<<<NBLK, 256, 0, stream>>>(x, gcn, bq, bk, bv, bo,
        ln1g, ln1b, b1, b2p, ln2g, ln2b, Wf,
        WswQ, WswK, WswV, WswO, Wsw1, Wsw2, PEt, acc1);
    num_stats_kernel<<<B_SZ / 16, 256, 0, stream>>>(num, Wn, bnum, ssum, ssq,
        nws, have_nws);
    if (have_nws) {
        bn_coef_kernel<<<1, 128, 0, stream>>>(ssum, ssq, bng, bnb, Wf, bfin, cvec);
        final_fast<<<B_SZ / 4, 256, 0, stream>>>(nws, cvec, acc1, (float*)d_out);
    } else {
        final_kernel<<<B_SZ, 128, 0, stream>>>(num, Wn, bnum, ssum, ssq, bng, bnb,
            Wf, bfin, acc1, (float*)d_out);
    }
}